// Round 1
// baseline (2049.818 us; speedup 1.0000x reference)
//
#include <hip/hip_runtime.h>
#include <math.h>

#define Nn 20000
#define Ee 120000
#define EALLe 240000
#define Cc 150
#define Rr 1000
#define EHd 300
#define RHd 100
#define CHd 150

static inline int cdiv_h(int a, int b){ return (a + b - 1) / b; }

__device__ __forceinline__ float lrelu01(float x){ return x > 0.f ? x : 0.01f * x; }

__device__ __forceinline__ float wredsum(float v){
#pragma unroll
  for (int m = 32; m >= 1; m >>= 1) v += __shfl_xor(v, m, 64);
  return v;
}

__device__ __forceinline__ void atomicMaxF(float* addr, float v){
  if (v >= 0.f) atomicMax((int*)addr, __float_as_int(v));
  else atomicMin((unsigned int*)addr, (unsigned int)__float_as_int(v));
}

__global__ void k_fill(float* p, float v, int n){
  int i = blockIdx.x * blockDim.x + threadIdx.x;
  if (i < n) p[i] = v;
}

// normalize r_emb rows + the 4 relation scalar tables (r_emb_n @ ar[k])
__global__ __launch_bounds__(64) void k_rnorm(const float* __restrict__ rt,
    const float* __restrict__ arh, const float* __restrict__ are,
    float* __restrict__ rn, float* __restrict__ ra0h, float* __restrict__ ra1h,
    float* __restrict__ ra0e, float* __restrict__ ra1e){
  int r = blockIdx.x, lane = threadIdx.x;
  bool m1 = (lane + 64 < RHd);
  float v0 = rt[r * RHd + lane];
  float v1 = m1 ? rt[r * RHd + lane + 64] : 0.f;
  float ss = wredsum(v0 * v0 + v1 * v1);
  float inv = 1.f / fmaxf(sqrtf(ss), 1e-12f);
  float n0 = v0 * inv, n1 = v1 * inv;
  rn[r * RHd + lane] = n0;
  if (m1) rn[r * RHd + lane + 64] = n1;
  float s;
  s = wredsum(n0 * arh[lane] + (m1 ? n1 * arh[lane + 64] : 0.f));
  if (!lane) ra0h[r] = s;
  s = wredsum(n0 * arh[RHd + lane] + (m1 ? n1 * arh[RHd + lane + 64] : 0.f));
  if (!lane) ra1h[r] = s;
  s = wredsum(n0 * are[lane] + (m1 ? n1 * are[lane + 64] : 0.f));
  if (!lane) ra0e[r] = s;
  s = wredsum(n0 * are[RHd + lane] + (m1 ? n1 * are[RHd + lane + 64] : 0.f));
  if (!lane) ra1e[r] = s;
}

__global__ void k_count(const int* __restrict__ dst, int* __restrict__ degi){
  int e = blockIdx.x * blockDim.x + threadIdx.x;
  if (e < EALLe) atomicAdd(&degi[dst[e]], 1);
}

__global__ void k_dis(const int* __restrict__ degi, float* __restrict__ dis){
  int n = blockIdx.x * blockDim.x + threadIdx.x;
  if (n < Nn) dis[n] = degi[n] > 0 ? rsqrtf((float)degi[n]) : 0.f;
}

// single-block exclusive scan of degi -> csr_ptr (and cursor copy)
__global__ __launch_bounds__(1024) void k_scan(const int* __restrict__ degi,
    int* __restrict__ ptr, int* __restrict__ cur){
  __shared__ int s[1024];
  int t = threadIdx.x;
  const int per = (Nn + 1023) / 1024;
  int b0 = t * per; if (b0 > Nn) b0 = Nn;
  int b1 = b0 + per; if (b1 > Nn) b1 = Nn;
  int sum = 0;
  for (int i = b0; i < b1; i++) sum += degi[i];
  s[t] = sum;
  __syncthreads();
  for (int off = 1; off < 1024; off <<= 1){
    int v = (t >= off) ? s[t - off] : 0;
    __syncthreads();
    s[t] += v;
    __syncthreads();
  }
  int run = (t > 0) ? s[t - 1] : 0;
  for (int i = b0; i < b1; i++){
    ptr[i] = run; cur[i] = run; run += degi[i];
  }
  if (t == 1023) ptr[Nn] = s[1023];
}

__global__ void k_scatter(const int* __restrict__ src, const int* __restrict__ dst,
    int* __restrict__ cur, int* __restrict__ csr_src){
  int e = blockIdx.x * blockDim.x + threadIdx.x;
  if (e >= EALLe) return;
  int pos = atomicAdd(&cur[dst[e]], 1);
  csr_src[pos] = src[e];
}

// GCN SpMM + relu: one wave per destination node
__global__ __launch_bounds__(64) void k_gcn(const float* __restrict__ x, int ldx,
    const int* __restrict__ ptr, const int* __restrict__ src,
    const float* __restrict__ dis, float* __restrict__ out){
  int i = blockIdx.x, lane = threadIdx.x;
  int p0 = ptr[i], p1 = ptr[i + 1];
  float di = dis[i];
  float a0 = 0.f, a1 = 0.f, a2 = 0.f, a3 = 0.f, a4 = 0.f;
  for (int k = p0; k < p1; k++){
    int j = src[k];
    float w = di * dis[j];
    const float* xr = x + (size_t)j * ldx;
    a0 += w * xr[lane];
    a1 += w * xr[lane + 64];
    a2 += w * xr[lane + 128];
    a3 += w * xr[lane + 192];
    if (lane < EHd - 256) a4 += w * xr[lane + 256];
  }
  float* orow = out + (size_t)i * EHd;
  orow[lane] = fmaxf(a0, 0.f);
  orow[lane + 64] = fmaxf(a1, 0.f);
  orow[lane + 128] = fmaxf(a2, 0.f);
  orow[lane + 192] = fmaxf(a3, 0.f);
  if (lane < EHd - 256) orow[lane + 256] = fmaxf(a4, 0.f);
}

// tiled f32 GEMM: out = epi( X[nrows,K] @ Wm[M,K]^T ). EPI 0=relu, 1=highway
template<int EPI>
__global__ __launch_bounds__(256) void k_gemm(
    const float* __restrict__ X, int ldx, int nrows,
    const float* __restrict__ Wm, int K, int M,
    const float* __restrict__ bias,
    const float* __restrict__ X2, int ldx2,
    float* __restrict__ out, int ldo){
  __shared__ float Xs[16][65];
  __shared__ float Ws[16][65];
  int t = threadIdx.x;
  int c0 = blockIdx.x * 64, r0 = blockIdx.y * 64;
  int tx = t & 15, ty = t >> 4;
  int lr = t >> 2, lk = (t & 3) * 4;
  float acc[4][4] = {};
  int ntk = (K + 15) >> 4;
  for (int kt = 0; kt < ntk; kt++){
    int k0 = kt << 4;
    int xr = r0 + lr, wr = c0 + lr;
#pragma unroll
    for (int q = 0; q < 4; q++){
      int kk = k0 + lk + q;
      Xs[lk + q][lr] = (xr < nrows && kk < K) ? X[(size_t)xr * ldx + kk] : 0.f;
      Ws[lk + q][lr] = (wr < M && kk < K) ? Wm[(size_t)wr * K + kk] : 0.f;
    }
    __syncthreads();
#pragma unroll
    for (int kk = 0; kk < 16; kk++){
      float a[4], b[4];
#pragma unroll
      for (int i = 0; i < 4; i++) a[i] = Xs[kk][ty * 4 + i];
#pragma unroll
      for (int j = 0; j < 4; j++) b[j] = Ws[kk][tx * 4 + j];
#pragma unroll
      for (int i = 0; i < 4; i++)
#pragma unroll
        for (int j = 0; j < 4; j++) acc[i][j] += a[i] * b[j];
    }
    __syncthreads();
  }
#pragma unroll
  for (int i = 0; i < 4; i++){
    int r = r0 + ty * 4 + i;
    if (r >= nrows) continue;
#pragma unroll
    for (int j = 0; j < 4; j++){
      int c = c0 + tx * 4 + j;
      if (c >= M) continue;
      float v = acc[i][j];
      float o;
      if (EPI == 0){
        o = fmaxf(v, 0.f);
      } else {
        float g = 1.f / (1.f + expf(-(v + bias[c])));
        o = g * X2[(size_t)r * ldx2 + c] + (1.f - g) * X[(size_t)r * ldx + c];
      }
      out[(size_t)r * ldo + c] = o;
    }
  }
}

// per-node dot products for gat_e: nm1 = xm.v1m ; no1/no2/no3/nv4 = xo.{v1o,v2o,v3o,v4}
__global__ __launch_bounds__(64) void k_ndots(
    const float* __restrict__ xm, const float* __restrict__ xo,
    const float* __restrict__ v1m, const float* __restrict__ v1o,
    const float* __restrict__ v2o, const float* __restrict__ v3o,
    const float* __restrict__ v4,
    float* __restrict__ nm1, float* __restrict__ no1, float* __restrict__ no2,
    float* __restrict__ no3, float* __restrict__ nv4){
  int n = blockIdx.x, lane = threadIdx.x;
  bool m2 = lane < (CHd - 128);
  const float* mr = xm + (size_t)n * CHd;
  const float* orw = xo + (size_t)n * CHd;
  float m0 = mr[lane], mv1 = mr[lane + 64], mv2 = m2 ? mr[lane + 128] : 0.f;
  float o0 = orw[lane], o1 = orw[lane + 64], o2 = m2 ? orw[lane + 128] : 0.f;
  float s;
  s = wredsum(m0 * v1m[lane] + mv1 * v1m[lane + 64] + (m2 ? mv2 * v1m[lane + 128] : 0.f));
  if (!lane) nm1[n] = s;
  s = wredsum(o0 * v1o[lane] + o1 * v1o[lane + 64] + (m2 ? o2 * v1o[lane + 128] : 0.f));
  if (!lane) no1[n] = s;
  s = wredsum(o0 * v2o[lane] + o1 * v2o[lane + 64] + (m2 ? o2 * v2o[lane + 128] : 0.f));
  if (!lane) no2[n] = s;
  s = wredsum(o0 * v3o[lane] + o1 * v3o[lane + 64] + (m2 ? o2 * v3o[lane + 128] : 0.f));
  if (!lane) no3[n] = s;
  s = wredsum(o0 * v4[lane] + o1 * v4[lane + 64] + (m2 ? o2 * v4[lane + 128] : 0.f));
  if (!lane) nv4[n] = s;
}

__global__ void k_e1(const int* __restrict__ im, const int* __restrict__ io,
    const int* __restrict__ rel, const int* __restrict__ trip,
    const float* __restrict__ ra0, const float* __restrict__ nm1,
    const float* __restrict__ no1, float* __restrict__ es1, float* __restrict__ tmax){
  int e = blockIdx.x * blockDim.x + threadIdx.x;
  if (e >= Ee) return;
  float v = 0.5f * (nm1[im[e]] + no1[io[e]]) + ra0[rel[e]];
  v = lrelu01(v);
  es1[e] = v;
  atomicMaxF(&tmax[trip[e]], v);
}

// es[e] = exp(es[e] - mx[seg[e]]) ; ssum[seg] += es[e]
__global__ void k_expsum(const int* __restrict__ seg, const float* __restrict__ mx,
    float* __restrict__ es, float* __restrict__ ssum){
  int e = blockIdx.x * blockDim.x + threadIdx.x;
  if (e >= Ee) return;
  float s = expf(es[e] - mx[seg[e]]);
  es[e] = s;
  atomicAdd(&ssum[seg[e]], s);
}

// per edge: x_edge = l2norm(xm[im]*alpha); fused dots with v3m/v2m -> e -> cmax
__global__ __launch_bounds__(256) void k_xedge(
    const float* __restrict__ xm, const int* __restrict__ im, const int* __restrict__ io,
    const int* __restrict__ rel, const int* __restrict__ trip, const int* __restrict__ ci,
    const float* __restrict__ tsum, const float* __restrict__ ra1,
    const float* __restrict__ no2, const float* __restrict__ no3,
    const float* __restrict__ v3m, const float* __restrict__ v2m,
    float* __restrict__ es1, float* __restrict__ xe,
    float* __restrict__ es2, float* __restrict__ cmax){
  int w = threadIdx.x >> 6, lane = threadIdx.x & 63;
  int e = blockIdx.x * 4 + w;
  if (e >= Ee) return;
  bool m2 = lane < (CHd - 128);
  float alpha = es1[e] / tsum[trip[e]];
  const float* xr = xm + (size_t)im[e] * CHd;
  float a0 = xr[lane] * alpha;
  float a1 = xr[lane + 64] * alpha;
  float a2 = m2 ? xr[lane + 128] * alpha : 0.f;
  float ss = wredsum(a0 * a0 + a1 * a1 + a2 * a2);
  float inv = 1.f / fmaxf(sqrtf(ss), 1e-12f);
  a0 *= inv; a1 *= inv; a2 *= inv;
  if (e < Nn){
    float* xo_ = xe + (size_t)e * CHd;
    xo_[lane] = a0; xo_[lane + 64] = a1;
    if (m2) xo_[lane + 128] = a2;
  }
  float d3 = wredsum(a0 * v3m[lane] + a1 * v3m[lane + 64] + (m2 ? a2 * v3m[lane + 128] : 0.f));
  float d2 = wredsum(a0 * v2m[lane] + a1 * v2m[lane + 64] + (m2 ? a2 * v2m[lane + 128] : 0.f));
  if (lane == 0){
    int iov = io[e];
    float er = 0.5f * (ra1[rel[e]] + 0.5f * (d3 + no3[iov]));
    float v = no2[iov] + er + d2;
    v = lrelu01(v);
    es2[e] = v;
    atomicMaxF(&cmax[ci[e]], v);
  }
}

__global__ __launch_bounds__(256) void k_xclass(
    const int* __restrict__ im, const int* __restrict__ ci,
    const float* __restrict__ es2, const float* __restrict__ csum,
    const float* __restrict__ xe, float* __restrict__ x_class){
  int w = threadIdx.x >> 6, lane = threadIdx.x & 63;
  int e = blockIdx.x * 4 + w;
  if (e >= Ee) return;
  int c = ci[e];
  float beta = es2[e] / csum[c];
  const float* xr = xe + (size_t)im[e] * CHd;
  float* xc = x_class + (size_t)c * CHd;
  atomicAdd(&xc[lane], beta * xr[lane]);
  atomicAdd(&xc[lane + 64], beta * xr[lane + 64]);
  if (lane < CHd - 128) atomicAdd(&xc[lane + 128], beta * xr[lane + 128]);
}

// single block: e_c, gama (segment softmax over cls_ent), scatter into outb
__global__ __launch_bounds__(256) void k_classfinal(
    const float* __restrict__ x_class, const float* __restrict__ acv,
    const float* __restrict__ nv4, const int* __restrict__ cls_ent,
    float* __restrict__ outb){
  __shared__ float v[Cc];
  __shared__ float g[Cc];
  __shared__ int ce[Cc];
  int t = threadIdx.x;
  if (t < Cc){
    ce[t] = cls_ent[t];
    float dot = 0.f;
    for (int f = 0; f < CHd; f++) dot += x_class[t * CHd + f] * acv[f];
    v[t] = lrelu01(dot + nv4[ce[t]]);
  }
  __syncthreads();
  if (t < Cc){
    int sgm = ce[t];
    float m = -3.0e38f;
    for (int c2 = 0; c2 < Cc; c2++) if (ce[c2] == sgm) m = fmaxf(m, v[c2]);
    float sum = 0.f;
    for (int c2 = 0; c2 < Cc; c2++) if (ce[c2] == sgm) sum += expf(v[c2] - m);
    g[t] = expf(v[t] - m) / sum;
  }
  __syncthreads();
  for (int idx = t; idx < Cc * CHd; idx += 256){
    int c = idx / CHd, f = idx - c * CHd;
    atomicAdd(&outb[(size_t)ce[c] * CHd + f], g[c] * x_class[c * CHd + f]);
  }
}

// per node dot of x1 row with gat_ai / gat_aj
__global__ __launch_bounds__(64) void k_s12(const float* __restrict__ x1,
    const float* __restrict__ ai, const float* __restrict__ aj,
    float* __restrict__ s1, float* __restrict__ s2){
  int n = blockIdx.x, lane = threadIdx.x;
  const float* xr = x1 + (size_t)n * 600;
  float sa = 0.f, sb = 0.f;
#pragma unroll
  for (int u = 0; u < 10; u++){
    int f = lane + u * 64;
    if (f < 600){
      float x = xr[f];
      sa += x * ai[f];
      sb += x * aj[f];
    }
  }
  sa = wredsum(sa); sb = wredsum(sb);
  if (!lane){ s1[n] = sa; s2[n] = sb; }
}

// final GAT over CSR + copy x into d_out[:, :300]
__global__ __launch_bounds__(256) void k_gat(const float* __restrict__ x1,
    const int* __restrict__ ptr, const int* __restrict__ src,
    const float* __restrict__ s1, const float* __restrict__ s2,
    float* __restrict__ dout){
  int i = blockIdx.x, t = threadIdx.x;
  float* orow = dout + (size_t)i * 900;
  const float* xi = x1 + (size_t)i * 600;
  for (int f = t; f < 300; f += 256) orow[f] = xi[f];
  int p0 = ptr[i], p1 = ptr[i + 1];
  if (p0 == p1){
    for (int f = t; f < 600; f += 256) orow[300 + f] = 0.f;
    return;
  }
  float s1i = s1[i];
  float m = -3.0e38f;
  for (int k = p0; k < p1; k++) m = fmaxf(m, lrelu01(s1i + s2[src[k]]));
  float acc0 = 0.f, acc1 = 0.f, acc2 = 0.f, den = 0.f;
  for (int k = p0; k < p1; k++){
    int j = src[k];
    float w = expf(lrelu01(s1i + s2[j]) - m);
    den += w;
    const float* xj = x1 + (size_t)j * 600;
    acc0 += w * xj[t];
    acc1 += w * xj[t + 256];
    if (t < 88) acc2 += w * xj[t + 512];
  }
  float invd = 1.f / den;
  orow[300 + t] = fmaxf(acc0 * invd, 0.f);
  orow[300 + t + 256] = fmaxf(acc1 * invd, 0.f);
  if (t < 88) orow[300 + t + 512] = fmaxf(acc2 * invd, 0.f);
}

extern "C" void kernel_launch(void* const* d_in, const int* in_sizes, int n_in,
                              void* d_out, int out_size, void* d_ws, size_t ws_size,
                              hipStream_t stream) {
  const float* x_e    = (const float*)d_in[0];
  const int*   ei     = (const int*)d_in[1];
  const int*   rel    = (const int*)d_in[2];
  const int*   eall   = (const int*)d_in[3];
  const int*   trip   = (const int*)d_in[4];
  const int*   cih    = (const int*)d_in[5];
  const int*   hcls   = (const int*)d_in[6];
  const int*   cit    = (const int*)d_in[7];
  const int*   tcls   = (const int*)d_in[8];
  const float* remb   = (const float*)d_in[9];
  const float* hw1w   = (const float*)d_in[10];
  const float* hw1b   = (const float*)d_in[11];
  const float* hw2w   = (const float*)d_in[12];
  const float* hw2b   = (const float*)d_in[13];
  const float* h2r_ac = (const float*)d_in[14];
  const float* h2r_ar = (const float*)d_in[15];
  const float* h2r_wh = (const float*)d_in[16];
  const float* h2r_wt = (const float*)d_in[17];
  const float* h2r_hww= (const float*)d_in[18];
  const float* h2r_hwb= (const float*)d_in[19];
  const float* et_ac  = (const float*)d_in[20];
  const float* et_ar  = (const float*)d_in[21];
  const float* et_wh  = (const float*)d_in[22];
  const float* et_wt  = (const float*)d_in[23];
  const float* et_hww = (const float*)d_in[24];
  const float* et_hwb = (const float*)d_in[25];
  const float* gai    = (const float*)d_in[26];
  const float* gaj    = (const float*)d_in[27];
  float* out = (float*)d_out;

  // ---- workspace allocator ----
  char* wsp = (char*)d_ws;
  auto alloc = [&](size_t nbytes) -> void* {
    void* p = (void*)wsp;
    wsp += (nbytes + 255) & ~(size_t)255;
    return p;
  };
  float* r_emb_n = (float*)alloc((size_t)Rr * RHd * 4);
  float* ra0h = (float*)alloc(Rr * 4);
  float* ra1h = (float*)alloc(Rr * 4);
  float* ra0e = (float*)alloc(Rr * 4);
  float* ra1e = (float*)alloc(Rr * 4);
  float* dis  = (float*)alloc(Nn * 4);
  int* degi    = (int*)alloc(Nn * 4);
  int* csr_ptr = (int*)alloc((Nn + 1) * 4);
  int* csr_cur = (int*)alloc(Nn * 4);
  int* csr_src = (int*)alloc((size_t)EALLe * 4);
  float* x1  = (float*)alloc((size_t)Nn * 600 * 4);
  float* xe  = (float*)alloc((size_t)Nn * CHd * 4);
  float* es1 = (float*)alloc((size_t)Ee * 4);
  float* es2 = (float*)alloc((size_t)Ee * 4);
  float* nm1 = (float*)alloc(Nn * 4);
  float* no1 = (float*)alloc(Nn * 4);
  float* no2 = (float*)alloc(Nn * 4);
  float* no3 = (float*)alloc(Nn * 4);
  float* nv4 = (float*)alloc(Nn * 4);
  float* tmax = (float*)alloc(Nn * 4);
  float* tsum = (float*)alloc(Nn * 4);
  float* cmax = (float*)alloc(Cc * 4);
  float* csum = (float*)alloc(Cc * 4);
  float* x_class = (float*)alloc(Cc * CHd * 4);
  float* s1v = (float*)alloc(Nn * 4);
  float* s2v = (float*)alloc(Nn * 4);

  // d_out doubles as scratch (fully rewritten by k_gat + hw epilogues at the end)
  float* bufA = out;                      // N*300 floats
  float* bufB = out + (size_t)Nn * EHd;   // N*300 floats
  float* outb = bufB;                     // N*150 view for gat_e class scatter

  // ---- prologue: r_emb norm, degrees, CSR ----
  hipMemsetAsync(degi, 0, Nn * 4, stream);
  k_rnorm<<<Rr, 64, 0, stream>>>(remb, h2r_ar, et_ar, r_emb_n, ra0h, ra1h, ra0e, ra1e);
  k_count<<<cdiv_h(EALLe, 256), 256, 0, stream>>>(eall + EALLe, degi);
  k_dis<<<cdiv_h(Nn, 256), 256, 0, stream>>>(degi, dis);
  k_scan<<<1, 1024, 0, stream>>>(degi, csr_ptr, csr_cur);
  k_scatter<<<cdiv_h(EALLe, 256), 256, 0, stream>>>(eall, eall + EALLe, csr_cur, csr_src);

  // ---- GCN + highway x2 ----
  k_gcn<<<Nn, 64, 0, stream>>>(x_e, EHd, csr_ptr, csr_src, dis, bufA);
  k_gemm<1><<<dim3(cdiv_h(EHd, 64), cdiv_h(Nn, 64)), 256, 0, stream>>>(
      x_e, EHd, Nn, hw1w, EHd, EHd, hw1b, bufA, EHd, bufB, EHd);
  k_gcn<<<Nn, 64, 0, stream>>>(bufB, EHd, csr_ptr, csr_src, dis, bufA);
  k_gemm<1><<<dim3(cdiv_h(EHd, 64), cdiv_h(Nn, 64)), 256, 0, stream>>>(
      bufB, EHd, Nn, hw2w, EHd, EHd, hw2b, bufA, EHd, x1, 600);

  // ---- gat_e (two calls) ----
  const int* eh = ei;
  const int* et = ei + Ee;
  float* xh = bufA;                    // relu(x @ wh.T)
  float* xt = bufA + (size_t)Nn * CHd; // relu(x @ wt.T)

  struct GP {
    const float* wh; const float* wt;
    const float* xm; const float* xo;
    const int* im; const int* io;
    const int* ci; const int* cls_ent;
    const float* ra0; const float* ra1;
    const float* v1m; const float* v1o;
    const float* v2m; const float* v2o;
    const float* v3m; const float* v3o;
    const float* v4;  const float* acv;
    const float* hww; const float* hwb;
    float* x1out;
  };
  // call A: x_e_h (main_is_head = False): xm = x_t, xo = x_h
  GP A = { h2r_wh, h2r_wt, xt, xh, et, eh, cih, hcls, ra0h, ra1h,
           h2r_ac + 4 * CHd, h2r_ac + 0 * CHd,
           h2r_ac + 5 * CHd, h2r_ac + 1 * CHd,
           h2r_ac + 6 * CHd, h2r_ac + 2 * CHd,
           h2r_ac + 3 * CHd, h2r_ac + 7 * CHd,
           h2r_hww, h2r_hwb, x1 + 300 };
  // call B: x_e_t (main_is_head = True): xm = x_h, xo = x_t
  GP B = { et_wh, et_wt, xh, xt, eh, et, cit, tcls, ra0e, ra1e,
           et_ac + 0 * CHd, et_ac + 4 * CHd,
           et_ac + 1 * CHd, et_ac + 5 * CHd,
           et_ac + 2 * CHd, et_ac + 6 * CHd,
           et_ac + 3 * CHd, et_ac + 7 * CHd,
           et_hww, et_hwb, x1 + 450 };

  GP calls[2] = { A, B };
  for (int ci_ = 0; ci_ < 2; ci_++){
    const GP& P = calls[ci_];
    // x_h / x_t
    k_gemm<0><<<dim3(cdiv_h(CHd, 64), cdiv_h(Nn, 64)), 256, 0, stream>>>(
        x1, 600, Nn, P.wh, EHd, CHd, nullptr, nullptr, 0, xh, CHd);
    k_gemm<0><<<dim3(cdiv_h(CHd, 64), cdiv_h(Nn, 64)), 256, 0, stream>>>(
        x1, 600, Nn, P.wt, EHd, CHd, nullptr, nullptr, 0, xt, CHd);
    // init segment buffers
    hipMemsetAsync(tsum, 0, Nn * 4, stream);
    hipMemsetAsync(csum, 0, Cc * 4, stream);
    hipMemsetAsync(x_class, 0, Cc * CHd * 4, stream);
    hipMemsetAsync(outb, 0, (size_t)Nn * CHd * 4, stream);
    k_fill<<<cdiv_h(Nn, 256), 256, 0, stream>>>(tmax, -INFINITY, Nn);
    k_fill<<<1, 256, 0, stream>>>(cmax, -INFINITY, Cc);
    // node dots
    k_ndots<<<Nn, 64, 0, stream>>>(P.xm, P.xo, P.v1m, P.v1o, P.v2o, P.v3o, P.v4,
                                   nm1, no1, no2, no3, nv4);
    // e1 + alpha softmax
    k_e1<<<cdiv_h(Ee, 256), 256, 0, stream>>>(P.im, P.io, rel, trip, P.ra0, nm1, no1, es1, tmax);
    k_expsum<<<cdiv_h(Ee, 256), 256, 0, stream>>>(trip, tmax, es1, tsum);
    // x_edge + fused e computation
    k_xedge<<<cdiv_h(Ee, 4), 256, 0, stream>>>(P.xm, P.im, P.io, rel, trip, P.ci,
        tsum, P.ra1, no2, no3, P.v3m, P.v2m, es1, xe, es2, cmax);
    // beta softmax + class aggregation
    k_expsum<<<cdiv_h(Ee, 256), 256, 0, stream>>>(P.ci, cmax, es2, csum);
    k_xclass<<<cdiv_h(Ee, 4), 256, 0, stream>>>(P.im, P.ci, es2, csum, xe, x_class);
    // e_c, gama, scatter
    k_classfinal<<<1, 256, 0, stream>>>(x_class, P.acv, nv4, P.cls_ent, outb);
    // final highway of this gat_e
    k_gemm<1><<<dim3(cdiv_h(CHd, 64), cdiv_h(Nn, 64)), 256, 0, stream>>>(
        P.xo, CHd, Nn, P.hww, CHd, CHd, P.hwb, outb, CHd, P.x1out, 600);
  }

  // ---- final GAT over x1 ----
  k_s12<<<Nn, 64, 0, stream>>>(x1, gai, gaj, s1v, s2v);
  k_gat<<<Nn, 256, 0, stream>>>(x1, csr_ptr, csr_src, s1v, s2v, out);
}

// Round 3
// 1712.120 us; speedup vs baseline: 1.1972x; 1.1972x over previous
//
#include <hip/hip_runtime.h>
#include <math.h>

#define Nn 20000
#define Ee 120000
#define EALLe 240000
#define Cc 150
#define Rr 1000
#define EHd 300
#define RHd 100
#define CHd 150

static inline int cdiv_h(int a, int b){ return (a + b - 1) / b; }

__device__ __forceinline__ float lrelu01(float x){ return x > 0.f ? x : 0.01f * x; }

__device__ __forceinline__ float wredsum(float v){
#pragma unroll
  for (int m = 32; m >= 1; m >>= 1) v += __shfl_xor(v, m, 64);
  return v;
}

template<int Kq>
__device__ __forceinline__ void wredsumN(float* v){
#pragma unroll
  for (int m = 32; m >= 1; m >>= 1){
#pragma unroll
    for (int k = 0; k < Kq; k++) v[k] += __shfl_xor(v[k], m, 64);
  }
}

__device__ __forceinline__ void atomicMaxF(float* addr, float v){
  if (v >= 0.f) atomicMax((int*)addr, __float_as_int(v));
  else atomicMin((unsigned int*)addr, (unsigned int)__float_as_int(v));
}

__global__ void k_fill(float* p, float v, int n){
  int i = blockIdx.x * blockDim.x + threadIdx.x;
  if (i < n) p[i] = v;
}

// normalize r_emb rows + the 2 live relation scalar tables (0.5 * r_emb_n @ ar[1])
__global__ __launch_bounds__(64) void k_rnorm(const float* __restrict__ rt,
    const float* __restrict__ arh, const float* __restrict__ are,
    float* __restrict__ ra1h, float* __restrict__ ra1e){
  int r = blockIdx.x, lane = threadIdx.x;
  bool m1 = (lane + 64 < RHd);
  float v0 = rt[r * RHd + lane];
  float v1 = m1 ? rt[r * RHd + lane + 64] : 0.f;
  float s[3];
  s[0] = v0 * v0 + v1 * v1;
  s[1] = v0 * arh[RHd + lane] + (m1 ? v1 * arh[RHd + lane + 64] : 0.f);
  s[2] = v0 * are[RHd + lane] + (m1 ? v1 * are[RHd + lane + 64] : 0.f);
  wredsumN<3>(s);
  float inv = 0.5f / fmaxf(sqrtf(s[0]), 1e-12f);   // fold the 0.5 factor of e_r
  if (!lane){
    ra1h[r] = s[1] * inv;
    ra1e[r] = s[2] * inv;
  }
}

__global__ void k_count(const int* __restrict__ dst, int* __restrict__ degi){
  int e = blockIdx.x * blockDim.x + threadIdx.x;
  if (e < EALLe) atomicAdd(&degi[dst[e]], 1);
}

__global__ void k_dis(const int* __restrict__ degi, float* __restrict__ dis){
  int n = blockIdx.x * blockDim.x + threadIdx.x;
  if (n < Nn) dis[n] = degi[n] > 0 ? rsqrtf((float)degi[n]) : 0.f;
}

// single-block exclusive scan of degi -> csr_ptr (and cursor copy)
__global__ __launch_bounds__(1024) void k_scan(const int* __restrict__ degi,
    int* __restrict__ ptr, int* __restrict__ cur){
  __shared__ int s[1024];
  int t = threadIdx.x;
  const int per = (Nn + 1023) / 1024;
  int b0 = t * per; if (b0 > Nn) b0 = Nn;
  int b1 = b0 + per; if (b1 > Nn) b1 = Nn;
  int sum = 0;
  for (int i = b0; i < b1; i++) sum += degi[i];
  s[t] = sum;
  __syncthreads();
  for (int off = 1; off < 1024; off <<= 1){
    int v = (t >= off) ? s[t - off] : 0;
    __syncthreads();
    s[t] += v;
    __syncthreads();
  }
  int run = (t > 0) ? s[t - 1] : 0;
  for (int i = b0; i < b1; i++){
    ptr[i] = run; cur[i] = run; run += degi[i];
  }
  if (t == 1023) ptr[Nn] = s[1023];
}

__global__ void k_scatter(const int* __restrict__ src, const int* __restrict__ dst,
    int* __restrict__ cur, int* __restrict__ csr_src){
  int e = blockIdx.x * blockDim.x + threadIdx.x;
  if (e >= EALLe) return;
  int pos = atomicAdd(&cur[dst[e]], 1);
  csr_src[pos] = src[e];
}

// GCN SpMM + relu: one wave per destination node
__global__ __launch_bounds__(64) void k_gcn(const float* __restrict__ x, int ldx,
    const int* __restrict__ ptr, const int* __restrict__ src,
    const float* __restrict__ dis, float* __restrict__ out){
  int i = blockIdx.x, lane = threadIdx.x;
  int p0 = ptr[i], p1 = ptr[i + 1];
  float di = dis[i];
  float a0 = 0.f, a1 = 0.f, a2 = 0.f, a3 = 0.f, a4 = 0.f;
  for (int k = p0; k < p1; k++){
    int j = src[k];
    float w = di * dis[j];
    const float* xr = x + (size_t)j * ldx;
    a0 += w * xr[lane];
    a1 += w * xr[lane + 64];
    a2 += w * xr[lane + 128];
    a3 += w * xr[lane + 192];
    if (lane < EHd - 256) a4 += w * xr[lane + 256];
  }
  float* orow = out + (size_t)i * EHd;
  orow[lane] = fmaxf(a0, 0.f);
  orow[lane + 64] = fmaxf(a1, 0.f);
  orow[lane + 128] = fmaxf(a2, 0.f);
  orow[lane + 192] = fmaxf(a3, 0.f);
  if (lane < EHd - 256) orow[lane + 256] = fmaxf(a4, 0.f);
}

// tiled f32 GEMM: out = epi( X[nrows,K] @ Wm[M,K]^T ). EPI 0=relu, 1=highway
template<int EPI>
__global__ __launch_bounds__(256) void k_gemm(
    const float* __restrict__ X, int ldx, int nrows,
    const float* __restrict__ Wm, int K, int M,
    const float* __restrict__ bias,
    const float* __restrict__ X2, int ldx2,
    float* __restrict__ out, int ldo){
  __shared__ float Xs[16][65];
  __shared__ float Ws[16][65];
  int t = threadIdx.x;
  int c0 = blockIdx.x * 64, r0 = blockIdx.y * 64;
  int tx = t & 15, ty = t >> 4;
  int lr = t >> 2, lk = (t & 3) * 4;
  float acc[4][4] = {};
  int ntk = (K + 15) >> 4;
  for (int kt = 0; kt < ntk; kt++){
    int k0 = kt << 4;
    int xr = r0 + lr, wr = c0 + lr;
#pragma unroll
    for (int q = 0; q < 4; q++){
      int kk = k0 + lk + q;
      Xs[lk + q][lr] = (xr < nrows && kk < K) ? X[(size_t)xr * ldx + kk] : 0.f;
      Ws[lk + q][lr] = (wr < M && kk < K) ? Wm[(size_t)wr * K + kk] : 0.f;
    }
    __syncthreads();
#pragma unroll
    for (int kk = 0; kk < 16; kk++){
      float a[4], b[4];
#pragma unroll
      for (int i = 0; i < 4; i++) a[i] = Xs[kk][ty * 4 + i];
#pragma unroll
      for (int j = 0; j < 4; j++) b[j] = Ws[kk][tx * 4 + j];
#pragma unroll
      for (int i = 0; i < 4; i++)
#pragma unroll
        for (int j = 0; j < 4; j++) acc[i][j] += a[i] * b[j];
    }
    __syncthreads();
  }
#pragma unroll
  for (int i = 0; i < 4; i++){
    int r = r0 + ty * 4 + i;
    if (r >= nrows) continue;
#pragma unroll
    for (int j = 0; j < 4; j++){
      int c = c0 + tx * 4 + j;
      if (c >= M) continue;
      float v = acc[i][j];
      float o;
      if (EPI == 0){
        o = fmaxf(v, 0.f);
      } else {
        float g = 1.f / (1.f + expf(-(v + bias[c])));
        o = g * X2[(size_t)r * ldx2 + c] + (1.f - g) * X[(size_t)r * ldx + c];
      }
      out[(size_t)r * ldo + c] = o;
    }
  }
}

// per-node precompute for gat_e:
//   xn  = l2norm(xm_row)                         [N,150]
//   pm  = xn.v2m + 0.25*xn.v3m                   [N]
//   po  = xo.v2o + 0.25*xo.v3o                   [N]
//   nv4 = xo.v4                                  [N]
__global__ __launch_bounds__(64) void k_ndots2(
    const float* __restrict__ xm, const float* __restrict__ xo,
    const float* __restrict__ v2m, const float* __restrict__ v3m,
    const float* __restrict__ v2o, const float* __restrict__ v3o,
    const float* __restrict__ v4,
    float* __restrict__ xn, float* __restrict__ pm,
    float* __restrict__ po, float* __restrict__ nv4){
  int n = blockIdx.x, lane = threadIdx.x;
  bool m2 = lane < (CHd - 128);
  const float* mr = xm + (size_t)n * CHd;
  const float* orw = xo + (size_t)n * CHd;
  float m0 = mr[lane], m1 = mr[lane + 64], mv2 = m2 ? mr[lane + 128] : 0.f;
  float o0 = orw[lane], o1 = orw[lane + 64], o2 = m2 ? orw[lane + 128] : 0.f;
  float s[4];
  // first pass: ||xm||^2 and the three xo dots (independent -> ILP in butterfly)
  s[0] = m0 * m0 + m1 * m1 + mv2 * mv2;
  s[1] = o0 * v2o[lane] + o1 * v2o[lane + 64] + (m2 ? o2 * v2o[lane + 128] : 0.f);
  s[2] = o0 * v3o[lane] + o1 * v3o[lane + 64] + (m2 ? o2 * v3o[lane + 128] : 0.f);
  s[3] = o0 * v4[lane]  + o1 * v4[lane + 64]  + (m2 ? o2 * v4[lane + 128]  : 0.f);
  wredsumN<4>(s);
  float inv = 1.f / fmaxf(sqrtf(s[0]), 1e-12f);
  float n0 = m0 * inv, n1 = m1 * inv, n2 = mv2 * inv;
  float* xr = xn + (size_t)n * CHd;
  xr[lane] = n0; xr[lane + 64] = n1;
  if (m2) xr[lane + 128] = n2;
  float d[2];
  d[0] = n0 * v2m[lane] + n1 * v2m[lane + 64] + (m2 ? n2 * v2m[lane + 128] : 0.f);
  d[1] = n0 * v3m[lane] + n1 * v3m[lane + 64] + (m2 ? n2 * v3m[lane + 128] : 0.f);
  wredsumN<2>(d);
  if (!lane){
    pm[n] = d[0] + 0.25f * d[1];
    po[n] = s[1] + 0.25f * s[2];
    nv4[n] = s[3];
  }
}

// im2[e] = im[im[e]]  (the literal x_edge[im] re-index)
__global__ void k_im2(const int* __restrict__ im, int* __restrict__ im2){
  int e = blockIdx.x * blockDim.x + threadIdx.x;
  if (e < Ee) im2[e] = im[im[e]];
}

// scalar per-edge logit for the beta softmax (alpha-independent form)
__global__ void k_e2(const int* __restrict__ im, const int* __restrict__ io,
    const int* __restrict__ rel, const int* __restrict__ ci,
    const float* __restrict__ pm, const float* __restrict__ po,
    const float* __restrict__ ra1,
    float* __restrict__ es2, float* __restrict__ cmax){
  int e = blockIdx.x * blockDim.x + threadIdx.x;
  if (e >= Ee) return;
  float v = lrelu01(po[io[e]] + pm[im[e]] + ra1[rel[e]]);
  es2[e] = v;
  atomicMaxF(&cmax[ci[e]], v);
}

// es[e] = exp(es[e] - mx[seg[e]]) ; ssum[seg] += es[e]
__global__ void k_expsum(const int* __restrict__ seg, const float* __restrict__ mx,
    float* __restrict__ es, float* __restrict__ ssum){
  int e = blockIdx.x * blockDim.x + threadIdx.x;
  if (e >= Ee) return;
  float s = expf(es[e] - mx[seg[e]]);
  es[e] = s;
  atomicAdd(&ssum[seg[e]], s);
}

__global__ __launch_bounds__(256) void k_xclass(
    const int* __restrict__ im2, const int* __restrict__ ci,
    const float* __restrict__ es2, const float* __restrict__ csum,
    const float* __restrict__ xn, float* __restrict__ x_class){
  int w = threadIdx.x >> 6, lane = threadIdx.x & 63;
  int e = blockIdx.x * 4 + w;
  if (e >= Ee) return;
  int c = ci[e];
  float beta = es2[e] / csum[c];
  const float* xr = xn + (size_t)im2[e] * CHd;
  float* xc = x_class + (size_t)c * CHd;
  atomicAdd(&xc[lane], beta * xr[lane]);
  atomicAdd(&xc[lane + 64], beta * xr[lane + 64]);
  if (lane < CHd - 128) atomicAdd(&xc[lane + 128], beta * xr[lane + 128]);
}

// single block: e_c, gama (segment softmax over cls_ent), scatter into outb
__global__ __launch_bounds__(256) void k_classfinal(
    const float* __restrict__ x_class, const float* __restrict__ acv,
    const float* __restrict__ nv4, const int* __restrict__ cls_ent,
    float* __restrict__ outb){
  __shared__ float v[Cc];
  __shared__ float g[Cc];
  __shared__ int ce[Cc];
  int t = threadIdx.x;
  if (t < Cc){
    ce[t] = cls_ent[t];
    float dot = 0.f;
    for (int f = 0; f < CHd; f++) dot += x_class[t * CHd + f] * acv[f];
    v[t] = lrelu01(dot + nv4[ce[t]]);
  }
  __syncthreads();
  if (t < Cc){
    int sgm = ce[t];
    float m = -3.0e38f;
    for (int c2 = 0; c2 < Cc; c2++) if (ce[c2] == sgm) m = fmaxf(m, v[c2]);
    float sum = 0.f;
    for (int c2 = 0; c2 < Cc; c2++) if (ce[c2] == sgm) sum += expf(v[c2] - m);
    g[t] = expf(v[t] - m) / sum;
  }
  __syncthreads();
  for (int idx = t; idx < Cc * CHd; idx += 256){
    int c = idx / CHd, f = idx - c * CHd;
    atomicAdd(&outb[(size_t)ce[c] * CHd + f], g[c] * x_class[c * CHd + f]);
  }
}

// per node dot of x1 row with gat_ai / gat_aj
__global__ __launch_bounds__(64) void k_s12(const float* __restrict__ x1,
    const float* __restrict__ ai, const float* __restrict__ aj,
    float* __restrict__ s1, float* __restrict__ s2){
  int n = blockIdx.x, lane = threadIdx.x;
  const float* xr = x1 + (size_t)n * 600;
  float sa = 0.f, sb = 0.f;
#pragma unroll
  for (int u = 0; u < 10; u++){
    int f = lane + u * 64;
    if (f < 600){
      float x = xr[f];
      sa += x * ai[f];
      sb += x * aj[f];
    }
  }
  float s[2] = { sa, sb };
  wredsumN<2>(s);
  if (!lane){ s1[n] = s[0]; s2[n] = s[1]; }
}

// final GAT over CSR + copy x into d_out[:, :300]
__global__ __launch_bounds__(256) void k_gat(const float* __restrict__ x1,
    const int* __restrict__ ptr, const int* __restrict__ src,
    const float* __restrict__ s1, const float* __restrict__ s2,
    float* __restrict__ dout){
  int i = blockIdx.x, t = threadIdx.x;
  float* orow = dout + (size_t)i * 900;
  const float* xi = x1 + (size_t)i * 600;
  for (int f = t; f < 300; f += 256) orow[f] = xi[f];
  int p0 = ptr[i], p1 = ptr[i + 1];
  if (p0 == p1){
    for (int f = t; f < 600; f += 256) orow[300 + f] = 0.f;
    return;
  }
  float s1i = s1[i];
  float m = -3.0e38f;
  for (int k = p0; k < p1; k++) m = fmaxf(m, lrelu01(s1i + s2[src[k]]));
  float acc0 = 0.f, acc1 = 0.f, acc2 = 0.f, den = 0.f;
  for (int k = p0; k < p1; k++){
    int j = src[k];
    float w = expf(lrelu01(s1i + s2[j]) - m);
    den += w;
    const float* xj = x1 + (size_t)j * 600;
    acc0 += w * xj[t];
    acc1 += w * xj[t + 256];
    if (t < 88) acc2 += w * xj[t + 512];
  }
  float invd = 1.f / den;
  orow[300 + t] = fmaxf(acc0 * invd, 0.f);
  orow[300 + t + 256] = fmaxf(acc1 * invd, 0.f);
  if (t < 88) orow[300 + t + 512] = fmaxf(acc2 * invd, 0.f);
}

extern "C" void kernel_launch(void* const* d_in, const int* in_sizes, int n_in,
                              void* d_out, int out_size, void* d_ws, size_t ws_size,
                              hipStream_t stream) {
  const float* x_e    = (const float*)d_in[0];
  const int*   ei     = (const int*)d_in[1];
  const int*   rel    = (const int*)d_in[2];
  const int*   eall   = (const int*)d_in[3];
  const int*   trip   = (const int*)d_in[4];
  const int*   cih    = (const int*)d_in[5];
  const int*   hcls   = (const int*)d_in[6];
  const int*   cit    = (const int*)d_in[7];
  const int*   tcls   = (const int*)d_in[8];
  const float* remb   = (const float*)d_in[9];
  const float* hw1w   = (const float*)d_in[10];
  const float* hw1b   = (const float*)d_in[11];
  const float* hw2w   = (const float*)d_in[12];
  const float* hw2b   = (const float*)d_in[13];
  const float* h2r_ac = (const float*)d_in[14];
  const float* h2r_ar = (const float*)d_in[15];
  const float* h2r_wh = (const float*)d_in[16];
  const float* h2r_wt = (const float*)d_in[17];
  const float* h2r_hww= (const float*)d_in[18];
  const float* h2r_hwb= (const float*)d_in[19];
  const float* et_ac  = (const float*)d_in[20];
  const float* et_ar  = (const float*)d_in[21];
  const float* et_wh  = (const float*)d_in[22];
  const float* et_wt  = (const float*)d_in[23];
  const float* et_hww = (const float*)d_in[24];
  const float* et_hwb = (const float*)d_in[25];
  const float* gai    = (const float*)d_in[26];
  const float* gaj    = (const float*)d_in[27];
  float* out = (float*)d_out;
  (void)trip;

  // ---- workspace allocator ----
  char* wsp = (char*)d_ws;
  auto alloc = [&](size_t nbytes) -> void* {
    void* p = (void*)wsp;
    wsp += (nbytes + 255) & ~(size_t)255;
    return p;
  };
  float* ra1h = (float*)alloc(Rr * 4);
  float* ra1e = (float*)alloc(Rr * 4);
  float* dis  = (float*)alloc(Nn * 4);
  int* degi    = (int*)alloc(Nn * 4);
  int* csr_ptr = (int*)alloc((Nn + 1) * 4);
  int* csr_cur = (int*)alloc(Nn * 4);
  int* csr_src = (int*)alloc((size_t)EALLe * 4);
  float* x1  = (float*)alloc((size_t)Nn * 600 * 4);
  float* xn  = (float*)alloc((size_t)Nn * CHd * 4);
  float* es2 = (float*)alloc((size_t)Ee * 4);
  int*   im2 = (int*)alloc((size_t)Ee * 4);
  float* pm  = (float*)alloc(Nn * 4);
  float* po  = (float*)alloc(Nn * 4);
  float* nv4 = (float*)alloc(Nn * 4);
  float* cmax = (float*)alloc(Cc * 4);
  float* csum = (float*)alloc(Cc * 4);
  float* x_class = (float*)alloc(Cc * CHd * 4);
  float* s1v = (float*)alloc(Nn * 4);
  float* s2v = (float*)alloc(Nn * 4);

  // d_out doubles as scratch (fully rewritten by k_gat at the end)
  float* bufA = out;                      // N*300 floats
  float* bufB = out + (size_t)Nn * EHd;   // N*300 floats
  float* outb = bufB;                     // N*150 view for gat_e class scatter

  // ---- prologue: r_emb norm, degrees, CSR ----
  hipMemsetAsync(degi, 0, Nn * 4, stream);
  k_rnorm<<<Rr, 64, 0, stream>>>(remb, h2r_ar, et_ar, ra1h, ra1e);
  k_count<<<cdiv_h(EALLe, 256), 256, 0, stream>>>(eall + EALLe, degi);
  k_dis<<<cdiv_h(Nn, 256), 256, 0, stream>>>(degi, dis);
  k_scan<<<1, 1024, 0, stream>>>(degi, csr_ptr, csr_cur);
  k_scatter<<<cdiv_h(EALLe, 256), 256, 0, stream>>>(eall, eall + EALLe, csr_cur, csr_src);

  // ---- GCN + highway x2 ----
  k_gcn<<<Nn, 64, 0, stream>>>(x_e, EHd, csr_ptr, csr_src, dis, bufA);
  k_gemm<1><<<dim3(cdiv_h(EHd, 64), cdiv_h(Nn, 64)), 256, 0, stream>>>(
      x_e, EHd, Nn, hw1w, EHd, EHd, hw1b, bufA, EHd, bufB, EHd);
  k_gcn<<<Nn, 64, 0, stream>>>(bufB, EHd, csr_ptr, csr_src, dis, bufA);
  k_gemm<1><<<dim3(cdiv_h(EHd, 64), cdiv_h(Nn, 64)), 256, 0, stream>>>(
      bufB, EHd, Nn, hw2w, EHd, EHd, hw2b, bufA, EHd, x1, 600);

  // ---- gat_e (two calls) ----
  const int* eh = ei;
  const int* et = ei + Ee;
  float* xh = bufA;                    // relu(x @ wh.T)
  float* xt = bufA + (size_t)Nn * CHd; // relu(x @ wt.T)

  struct GP {
    const float* wh; const float* wt;
    const float* xm; const float* xo;
    const int* im; const int* io;
    const int* ci; const int* cls_ent;
    const float* ra1;
    const float* v2m; const float* v2o;
    const float* v3m; const float* v3o;
    const float* v4;  const float* acv;
    const float* hww; const float* hwb;
    float* x1out;
  };
  // call A: x_e_h (main_is_head = False): xm = x_t, xo = x_h
  GP A = { h2r_wh, h2r_wt, xt, xh, et, eh, cih, hcls, ra1h,
           h2r_ac + 5 * CHd, h2r_ac + 1 * CHd,
           h2r_ac + 6 * CHd, h2r_ac + 2 * CHd,
           h2r_ac + 3 * CHd, h2r_ac + 7 * CHd,
           h2r_hww, h2r_hwb, x1 + 300 };
  // call B: x_e_t (main_is_head = True): xm = x_h, xo = x_t
  GP B = { et_wh, et_wt, xh, xt, eh, et, cit, tcls, ra1e,
           et_ac + 1 * CHd, et_ac + 5 * CHd,
           et_ac + 2 * CHd, et_ac + 6 * CHd,
           et_ac + 3 * CHd, et_ac + 7 * CHd,
           et_hww, et_hwb, x1 + 450 };

  GP calls[2] = { A, B };
  for (int ci_ = 0; ci_ < 2; ci_++){
    const GP& P = calls[ci_];
    // x_h / x_t
    k_gemm<0><<<dim3(cdiv_h(CHd, 64), cdiv_h(Nn, 64)), 256, 0, stream>>>(
        x1, 600, Nn, P.wh, EHd, CHd, nullptr, nullptr, 0, xh, CHd);
    k_gemm<0><<<dim3(cdiv_h(CHd, 64), cdiv_h(Nn, 64)), 256, 0, stream>>>(
        x1, 600, Nn, P.wt, EHd, CHd, nullptr, nullptr, 0, xt, CHd);
    // init segment buffers
    hipMemsetAsync(csum, 0, Cc * 4, stream);
    hipMemsetAsync(x_class, 0, Cc * CHd * 4, stream);
    hipMemsetAsync(outb, 0, (size_t)Nn * CHd * 4, stream);
    k_fill<<<1, 256, 0, stream>>>(cmax, -INFINITY, Cc);
    // per-node precompute (xn, pm, po, nv4)
    k_ndots2<<<Nn, 64, 0, stream>>>(P.xm, P.xo, P.v2m, P.v3m, P.v2o, P.v3o, P.v4,
                                    xn, pm, po, nv4);
    // im2 = im[im]
    k_im2<<<cdiv_h(Ee, 256), 256, 0, stream>>>(P.im, im2);
    // per-edge logit + beta softmax
    k_e2<<<cdiv_h(Ee, 256), 256, 0, stream>>>(P.im, P.io, rel, P.ci, pm, po, P.ra1,
                                              es2, cmax);
    k_expsum<<<cdiv_h(Ee, 256), 256, 0, stream>>>(P.ci, cmax, es2, csum);
    // class aggregation
    k_xclass<<<cdiv_h(Ee, 4), 256, 0, stream>>>(im2, P.ci, es2, csum, xn, x_class);
    // e_c, gama, scatter
    k_classfinal<<<1, 256, 0, stream>>>(x_class, P.acv, nv4, P.cls_ent, outb);
    // final highway of this gat_e
    k_gemm<1><<<dim3(cdiv_h(CHd, 64), cdiv_h(Nn, 64)), 256, 0, stream>>>(
        P.xo, CHd, Nn, P.hww, CHd, CHd, P.hwb, outb, CHd, P.x1out, 600);
  }

  // ---- final GAT over x1 ----
  k_s12<<<Nn, 64, 0, stream>>>(x1, gai, gaj, s1v, s2v);
  k_gat<<<Nn, 256, 0, stream>>>(x1, csr_ptr, csr_src, s1v, s2v, out);
}

// Round 4
// 1468.307 us; speedup vs baseline: 1.3960x; 1.1661x over previous
//
#include <hip/hip_runtime.h>
#include <math.h>

#define Nn 20000
#define Ee 120000
#define EALLe 240000
#define Cc 150
#define Rr 1000
#define EHd 300
#define RHd 100
#define CHd 150

static inline int cdiv_h(int a, int b){ return (a + b - 1) / b; }

__device__ __forceinline__ float lrelu01(float x){ return x > 0.f ? x : 0.01f * x; }

__device__ __forceinline__ float wredsum(float v){
#pragma unroll
  for (int m = 32; m >= 1; m >>= 1) v += __shfl_xor(v, m, 64);
  return v;
}

template<int Kq>
__device__ __forceinline__ void wredsumN(float* v){
#pragma unroll
  for (int m = 32; m >= 1; m >>= 1){
#pragma unroll
    for (int k = 0; k < Kq; k++) v[k] += __shfl_xor(v[k], m, 64);
  }
}

__device__ __forceinline__ void atomicMaxF(float* addr, float v){
  if (v >= 0.f) atomicMax((int*)addr, __float_as_int(v));
  else atomicMin((unsigned int*)addr, (unsigned int)__float_as_int(v));
}

__global__ void k_fill(float* p, float v, int n){
  int i = blockIdx.x * blockDim.x + threadIdx.x;
  if (i < n) p[i] = v;
}

// normalize r_emb rows + the 2 live relation scalar tables (0.5 * r_emb_n @ ar[1])
__global__ __launch_bounds__(64) void k_rnorm(const float* __restrict__ rt,
    const float* __restrict__ arh, const float* __restrict__ are,
    float* __restrict__ ra1h, float* __restrict__ ra1e){
  int r = blockIdx.x, lane = threadIdx.x;
  bool m1 = (lane + 64 < RHd);
  float v0 = rt[r * RHd + lane];
  float v1 = m1 ? rt[r * RHd + lane + 64] : 0.f;
  float s[3];
  s[0] = v0 * v0 + v1 * v1;
  s[1] = v0 * arh[RHd + lane] + (m1 ? v1 * arh[RHd + lane + 64] : 0.f);
  s[2] = v0 * are[RHd + lane] + (m1 ? v1 * are[RHd + lane + 64] : 0.f);
  wredsumN<3>(s);
  float inv = 0.5f / fmaxf(sqrtf(s[0]), 1e-12f);   // fold the 0.5 factor of e_r
  if (!lane){
    ra1h[r] = s[1] * inv;
    ra1e[r] = s[2] * inv;
  }
}

__global__ void k_count(const int* __restrict__ dst, int* __restrict__ degi){
  int e = blockIdx.x * blockDim.x + threadIdx.x;
  if (e < EALLe) atomicAdd(&degi[dst[e]], 1);
}

__global__ void k_dis(const int* __restrict__ degi, float* __restrict__ dis){
  int n = blockIdx.x * blockDim.x + threadIdx.x;
  if (n < Nn) dis[n] = degi[n] > 0 ? rsqrtf((float)degi[n]) : 0.f;
}

// single-block exclusive scan of degi -> csr_ptr (and cursor copy)
__global__ __launch_bounds__(1024) void k_scan(const int* __restrict__ degi,
    int* __restrict__ ptr, int* __restrict__ cur){
  __shared__ int s[1024];
  int t = threadIdx.x;
  const int per = (Nn + 1023) / 1024;
  int b0 = t * per; if (b0 > Nn) b0 = Nn;
  int b1 = b0 + per; if (b1 > Nn) b1 = Nn;
  int sum = 0;
  for (int i = b0; i < b1; i++) sum += degi[i];
  s[t] = sum;
  __syncthreads();
  for (int off = 1; off < 1024; off <<= 1){
    int v = (t >= off) ? s[t - off] : 0;
    __syncthreads();
    s[t] += v;
    __syncthreads();
  }
  int run = (t > 0) ? s[t - 1] : 0;
  for (int i = b0; i < b1; i++){
    ptr[i] = run; cur[i] = run; run += degi[i];
  }
  if (t == 1023) ptr[Nn] = s[1023];
}

__global__ void k_scatter(const int* __restrict__ src, const int* __restrict__ dst,
    int* __restrict__ cur, int* __restrict__ csr_src){
  int e = blockIdx.x * blockDim.x + threadIdx.x;
  if (e >= EALLe) return;
  int pos = atomicAdd(&cur[dst[e]], 1);
  csr_src[pos] = src[e];
}

// GCN SpMM + relu: one wave per destination node
__global__ __launch_bounds__(64) void k_gcn(const float* __restrict__ x, int ldx,
    const int* __restrict__ ptr, const int* __restrict__ src,
    const float* __restrict__ dis, float* __restrict__ out){
  int i = blockIdx.x, lane = threadIdx.x;
  int p0 = ptr[i], p1 = ptr[i + 1];
  float di = dis[i];
  float a0 = 0.f, a1 = 0.f, a2 = 0.f, a3 = 0.f, a4 = 0.f;
  for (int k = p0; k < p1; k++){
    int j = src[k];
    float w = di * dis[j];
    const float* xr = x + (size_t)j * ldx;
    a0 += w * xr[lane];
    a1 += w * xr[lane + 64];
    a2 += w * xr[lane + 128];
    a3 += w * xr[lane + 192];
    if (lane < EHd - 256) a4 += w * xr[lane + 256];
  }
  float* orow = out + (size_t)i * EHd;
  orow[lane] = fmaxf(a0, 0.f);
  orow[lane + 64] = fmaxf(a1, 0.f);
  orow[lane + 128] = fmaxf(a2, 0.f);
  orow[lane + 192] = fmaxf(a3, 0.f);
  if (lane < EHd - 256) orow[lane + 256] = fmaxf(a4, 0.f);
}

// tiled f32 GEMM: out = epi( X[nrows,K] @ Wm[M,K]^T ). EPI 0=relu, 1=highway
// 128-row x 64-col block, 256 threads, 8x4 micro-tile, K-tile 16.
// LDS k-major: fragment A-reads are 16-lane broadcasts, B-reads 2-way (free).
template<int EPI>
__global__ __launch_bounds__(256) void k_gemm(
    const float* __restrict__ X, int ldx, int nrows,
    const float* __restrict__ Wm, int K, int M,
    const float* __restrict__ bias,
    const float* __restrict__ X2, int ldx2,
    float* __restrict__ out, int ldo){
  __shared__ float Xs[16][132];
  __shared__ float Ws[16][68];
  int t = threadIdx.x;
  int c0 = blockIdx.x * 64, r0 = blockIdx.y * 128;
  int tx = t & 15, ty = t >> 4;          // micro-tile: rows ty*8..+7, cols tx*4..+3
  int lrow = t >> 2, lk = (t & 3) * 4;   // staging: 2 X-rows + 1 W-row, 4 k each
  int xr0 = r0 + lrow, xr1 = r0 + lrow + 64;
  int wr = c0 + lrow;
  const bool v4x = ((ldx & 3) == 0);
  const bool v4w = ((K & 3) == 0);
  float acc[8][4] = {};
  for (int k0 = 0; k0 < K; k0 += 16){
    bool kfull = (k0 + 16 <= K);
    float a0[4] = {0.f,0.f,0.f,0.f}, a1[4] = {0.f,0.f,0.f,0.f}, wv[4] = {0.f,0.f,0.f,0.f};
    if (kfull && v4x){
      if (xr0 < nrows) *(float4*)a0 = *(const float4*)&X[(size_t)xr0 * ldx + k0 + lk];
      if (xr1 < nrows) *(float4*)a1 = *(const float4*)&X[(size_t)xr1 * ldx + k0 + lk];
    } else {
#pragma unroll
      for (int q = 0; q < 4; q++){
        int kk = k0 + lk + q;
        if (kk < K){
          if (xr0 < nrows) a0[q] = X[(size_t)xr0 * ldx + kk];
          if (xr1 < nrows) a1[q] = X[(size_t)xr1 * ldx + kk];
        }
      }
    }
    if (kfull && v4w){
      if (wr < M) *(float4*)wv = *(const float4*)&Wm[(size_t)wr * K + k0 + lk];
    } else {
#pragma unroll
      for (int q = 0; q < 4; q++){
        int kk = k0 + lk + q;
        if (kk < K && wr < M) wv[q] = Wm[(size_t)wr * K + kk];
      }
    }
    __syncthreads();
#pragma unroll
    for (int q = 0; q < 4; q++){
      Xs[lk + q][lrow]      = a0[q];
      Xs[lk + q][lrow + 64] = a1[q];
      Ws[lk + q][lrow]      = wv[q];
    }
    __syncthreads();
#pragma unroll
    for (int kk = 0; kk < 16; kk++){
      float av[8], bv[4];
#pragma unroll
      for (int i = 0; i < 8; i++) av[i] = Xs[kk][ty * 8 + i];
#pragma unroll
      for (int j = 0; j < 4; j++) bv[j] = Ws[kk][tx * 4 + j];
#pragma unroll
      for (int i = 0; i < 8; i++)
#pragma unroll
        for (int j = 0; j < 4; j++) acc[i][j] += av[i] * bv[j];
    }
  }
#pragma unroll
  for (int i = 0; i < 8; i++){
    int r = r0 + ty * 8 + i;
    if (r >= nrows) continue;
#pragma unroll
    for (int j = 0; j < 4; j++){
      int c = c0 + tx * 4 + j;
      if (c >= M) continue;
      float v = acc[i][j];
      float o;
      if (EPI == 0){
        o = fmaxf(v, 0.f);
      } else {
        float g = 1.f / (1.f + expf(-(v + bias[c])));
        o = g * X2[(size_t)r * ldx2 + c] + (1.f - g) * X[(size_t)r * ldx + c];
      }
      out[(size_t)r * ldo + c] = o;
    }
  }
}

// per-node precompute for gat_e:
//   xn  = l2norm(xm_row)                         [N,150]
//   pm  = xn.v2m + 0.25*xn.v3m                   [N]
//   po  = xo.v2o + 0.25*xo.v3o                   [N]
//   nv4 = xo.v4                                  [N]
__global__ __launch_bounds__(64) void k_ndots2(
    const float* __restrict__ xm, const float* __restrict__ xo,
    const float* __restrict__ v2m, const float* __restrict__ v3m,
    const float* __restrict__ v2o, const float* __restrict__ v3o,
    const float* __restrict__ v4,
    float* __restrict__ xn, float* __restrict__ pm,
    float* __restrict__ po, float* __restrict__ nv4){
  int n = blockIdx.x, lane = threadIdx.x;
  bool m2 = lane < (CHd - 128);
  const float* mr = xm + (size_t)n * CHd;
  const float* orw = xo + (size_t)n * CHd;
  float m0 = mr[lane], m1 = mr[lane + 64], mv2 = m2 ? mr[lane + 128] : 0.f;
  float o0 = orw[lane], o1 = orw[lane + 64], o2 = m2 ? orw[lane + 128] : 0.f;
  float s[4];
  // first pass: ||xm||^2 and the three xo dots (independent -> ILP in butterfly)
  s[0] = m0 * m0 + m1 * m1 + mv2 * mv2;
  s[1] = o0 * v2o[lane] + o1 * v2o[lane + 64] + (m2 ? o2 * v2o[lane + 128] : 0.f);
  s[2] = o0 * v3o[lane] + o1 * v3o[lane + 64] + (m2 ? o2 * v3o[lane + 128] : 0.f);
  s[3] = o0 * v4[lane]  + o1 * v4[lane + 64]  + (m2 ? o2 * v4[lane + 128]  : 0.f);
  wredsumN<4>(s);
  float inv = 1.f / fmaxf(sqrtf(s[0]), 1e-12f);
  float n0 = m0 * inv, n1 = m1 * inv, n2 = mv2 * inv;
  float* xr = xn + (size_t)n * CHd;
  xr[lane] = n0; xr[lane + 64] = n1;
  if (m2) xr[lane + 128] = n2;
  float d[2];
  d[0] = n0 * v2m[lane] + n1 * v2m[lane + 64] + (m2 ? n2 * v2m[lane + 128] : 0.f);
  d[1] = n0 * v3m[lane] + n1 * v3m[lane + 64] + (m2 ? n2 * v3m[lane + 128] : 0.f);
  wredsumN<2>(d);
  if (!lane){
    pm[n] = d[0] + 0.25f * d[1];
    po[n] = s[1] + 0.25f * s[2];
    nv4[n] = s[3];
  }
}

// im2[e] = im[im[e]]  (the literal x_edge[im] re-index)
__global__ void k_im2(const int* __restrict__ im, int* __restrict__ im2){
  int e = blockIdx.x * blockDim.x + threadIdx.x;
  if (e < Ee) im2[e] = im[im[e]];
}

// scalar per-edge logit for the beta softmax (alpha-independent form)
__global__ void k_e2(const int* __restrict__ im, const int* __restrict__ io,
    const int* __restrict__ rel, const int* __restrict__ ci,
    const float* __restrict__ pm, const float* __restrict__ po,
    const float* __restrict__ ra1,
    float* __restrict__ es2, float* __restrict__ cmax){
  int e = blockIdx.x * blockDim.x + threadIdx.x;
  if (e >= Ee) return;
  float v = lrelu01(po[io[e]] + pm[im[e]] + ra1[rel[e]]);
  es2[e] = v;
  atomicMaxF(&cmax[ci[e]], v);
}

// es[e] = exp(es[e] - mx[seg[e]]) ; ssum[seg] += es[e]
__global__ void k_expsum(const int* __restrict__ seg, const float* __restrict__ mx,
    float* __restrict__ es, float* __restrict__ ssum){
  int e = blockIdx.x * blockDim.x + threadIdx.x;
  if (e >= Ee) return;
  float s = expf(es[e] - mx[seg[e]]);
  es[e] = s;
  atomicAdd(&ssum[seg[e]], s);
}

__global__ __launch_bounds__(256) void k_xclass(
    const int* __restrict__ im2, const int* __restrict__ ci,
    const float* __restrict__ es2, const float* __restrict__ csum,
    const float* __restrict__ xn, float* __restrict__ x_class){
  int w = threadIdx.x >> 6, lane = threadIdx.x & 63;
  int e = blockIdx.x * 4 + w;
  if (e >= Ee) return;
  int c = ci[e];
  float beta = es2[e] / csum[c];
  const float* xr = xn + (size_t)im2[e] * CHd;
  float* xc = x_class + (size_t)c * CHd;
  atomicAdd(&xc[lane], beta * xr[lane]);
  atomicAdd(&xc[lane + 64], beta * xr[lane + 64]);
  if (lane < CHd - 128) atomicAdd(&xc[lane + 128], beta * xr[lane + 128]);
}

// single block: e_c, gama (segment softmax over cls_ent), scatter into outb
__global__ __launch_bounds__(256) void k_classfinal(
    const float* __restrict__ x_class, const float* __restrict__ acv,
    const float* __restrict__ nv4, const int* __restrict__ cls_ent,
    float* __restrict__ outb){
  __shared__ float v[Cc];
  __shared__ float g[Cc];
  __shared__ int ce[Cc];
  int t = threadIdx.x;
  if (t < Cc){
    ce[t] = cls_ent[t];
    float dot = 0.f;
    for (int f = 0; f < CHd; f++) dot += x_class[t * CHd + f] * acv[f];
    v[t] = lrelu01(dot + nv4[ce[t]]);
  }
  __syncthreads();
  if (t < Cc){
    int sgm = ce[t];
    float m = -3.0e38f;
    for (int c2 = 0; c2 < Cc; c2++) if (ce[c2] == sgm) m = fmaxf(m, v[c2]);
    float sum = 0.f;
    for (int c2 = 0; c2 < Cc; c2++) if (ce[c2] == sgm) sum += expf(v[c2] - m);
    g[t] = expf(v[t] - m) / sum;
  }
  __syncthreads();
  for (int idx = t; idx < Cc * CHd; idx += 256){
    int c = idx / CHd, f = idx - c * CHd;
    atomicAdd(&outb[(size_t)ce[c] * CHd + f], g[c] * x_class[c * CHd + f]);
  }
}

// per node dot of x1 row with gat_ai / gat_aj
__global__ __launch_bounds__(64) void k_s12(const float* __restrict__ x1,
    const float* __restrict__ ai, const float* __restrict__ aj,
    float* __restrict__ s1, float* __restrict__ s2){
  int n = blockIdx.x, lane = threadIdx.x;
  const float* xr = x1 + (size_t)n * 600;
  float sa = 0.f, sb = 0.f;
#pragma unroll
  for (int u = 0; u < 10; u++){
    int f = lane + u * 64;
    if (f < 600){
      float x = xr[f];
      sa += x * ai[f];
      sb += x * aj[f];
    }
  }
  float s[2] = { sa, sb };
  wredsumN<2>(s);
  if (!lane){ s1[n] = s[0]; s2[n] = s[1]; }
}

// final GAT over CSR + copy x into d_out[:, :300]
__global__ __launch_bounds__(256) void k_gat(const float* __restrict__ x1,
    const int* __restrict__ ptr, const int* __restrict__ src,
    const float* __restrict__ s1, const float* __restrict__ s2,
    float* __restrict__ dout){
  int i = blockIdx.x, t = threadIdx.x;
  float* orow = dout + (size_t)i * 900;
  const float* xi = x1 + (size_t)i * 600;
  for (int f = t; f < 300; f += 256) orow[f] = xi[f];
  int p0 = ptr[i], p1 = ptr[i + 1];
  if (p0 == p1){
    for (int f = t; f < 600; f += 256) orow[300 + f] = 0.f;
    return;
  }
  float s1i = s1[i];
  float m = -3.0e38f;
  for (int k = p0; k < p1; k++) m = fmaxf(m, lrelu01(s1i + s2[src[k]]));
  float acc0 = 0.f, acc1 = 0.f, acc2 = 0.f, den = 0.f;
  for (int k = p0; k < p1; k++){
    int j = src[k];
    float w = expf(lrelu01(s1i + s2[j]) - m);
    den += w;
    const float* xj = x1 + (size_t)j * 600;
    acc0 += w * xj[t];
    acc1 += w * xj[t + 256];
    if (t < 88) acc2 += w * xj[t + 512];
  }
  float invd = 1.f / den;
  orow[300 + t] = fmaxf(acc0 * invd, 0.f);
  orow[300 + t + 256] = fmaxf(acc1 * invd, 0.f);
  if (t < 88) orow[300 + t + 512] = fmaxf(acc2 * invd, 0.f);
}

extern "C" void kernel_launch(void* const* d_in, const int* in_sizes, int n_in,
                              void* d_out, int out_size, void* d_ws, size_t ws_size,
                              hipStream_t stream) {
  const float* x_e    = (const float*)d_in[0];
  const int*   ei     = (const int*)d_in[1];
  const int*   rel    = (const int*)d_in[2];
  const int*   eall   = (const int*)d_in[3];
  const int*   trip   = (const int*)d_in[4];
  const int*   cih    = (const int*)d_in[5];
  const int*   hcls   = (const int*)d_in[6];
  const int*   cit    = (const int*)d_in[7];
  const int*   tcls   = (const int*)d_in[8];
  const float* remb   = (const float*)d_in[9];
  const float* hw1w   = (const float*)d_in[10];
  const float* hw1b   = (const float*)d_in[11];
  const float* hw2w   = (const float*)d_in[12];
  const float* hw2b   = (const float*)d_in[13];
  const float* h2r_ac = (const float*)d_in[14];
  const float* h2r_ar = (const float*)d_in[15];
  const float* h2r_wh = (const float*)d_in[16];
  const float* h2r_wt = (const float*)d_in[17];
  const float* h2r_hww= (const float*)d_in[18];
  const float* h2r_hwb= (const float*)d_in[19];
  const float* et_ac  = (const float*)d_in[20];
  const float* et_ar  = (const float*)d_in[21];
  const float* et_wh  = (const float*)d_in[22];
  const float* et_wt  = (const float*)d_in[23];
  const float* et_hww = (const float*)d_in[24];
  const float* et_hwb = (const float*)d_in[25];
  const float* gai    = (const float*)d_in[26];
  const float* gaj    = (const float*)d_in[27];
  float* out = (float*)d_out;
  (void)trip;

  // ---- workspace allocator ----
  char* wsp = (char*)d_ws;
  auto alloc = [&](size_t nbytes) -> void* {
    void* p = (void*)wsp;
    wsp += (nbytes + 255) & ~(size_t)255;
    return p;
  };
  float* ra1h = (float*)alloc(Rr * 4);
  float* ra1e = (float*)alloc(Rr * 4);
  float* dis  = (float*)alloc(Nn * 4);
  int* degi    = (int*)alloc(Nn * 4);
  int* csr_ptr = (int*)alloc((Nn + 1) * 4);
  int* csr_cur = (int*)alloc(Nn * 4);
  int* csr_src = (int*)alloc((size_t)EALLe * 4);
  float* x1  = (float*)alloc((size_t)Nn * 600 * 4);
  float* xn  = (float*)alloc((size_t)Nn * CHd * 4);
  float* es2 = (float*)alloc((size_t)Ee * 4);
  int*   im2 = (int*)alloc((size_t)Ee * 4);
  float* pm  = (float*)alloc(Nn * 4);
  float* po  = (float*)alloc(Nn * 4);
  float* nv4 = (float*)alloc(Nn * 4);
  float* cmax = (float*)alloc(Cc * 4);
  float* csum = (float*)alloc(Cc * 4);
  float* x_class = (float*)alloc(Cc * CHd * 4);
  float* s1v = (float*)alloc(Nn * 4);
  float* s2v = (float*)alloc(Nn * 4);

  // d_out doubles as scratch (fully rewritten by k_gat at the end)
  float* bufA = out;                      // N*300 floats
  float* bufB = out + (size_t)Nn * EHd;   // N*300 floats
  float* outb = bufB;                     // N*150 view for gat_e class scatter

  // ---- prologue: r_emb norm, degrees, CSR ----
  hipMemsetAsync(degi, 0, Nn * 4, stream);
  k_rnorm<<<Rr, 64, 0, stream>>>(remb, h2r_ar, et_ar, ra1h, ra1e);
  k_count<<<cdiv_h(EALLe, 256), 256, 0, stream>>>(eall + EALLe, degi);
  k_dis<<<cdiv_h(Nn, 256), 256, 0, stream>>>(degi, dis);
  k_scan<<<1, 1024, 0, stream>>>(degi, csr_ptr, csr_cur);
  k_scatter<<<cdiv_h(EALLe, 256), 256, 0, stream>>>(eall, eall + EALLe, csr_cur, csr_src);

  // ---- GCN + highway x2 ----
  k_gcn<<<Nn, 64, 0, stream>>>(x_e, EHd, csr_ptr, csr_src, dis, bufA);
  k_gemm<1><<<dim3(cdiv_h(EHd, 64), cdiv_h(Nn, 128)), 256, 0, stream>>>(
      x_e, EHd, Nn, hw1w, EHd, EHd, hw1b, bufA, EHd, bufB, EHd);
  k_gcn<<<Nn, 64, 0, stream>>>(bufB, EHd, csr_ptr, csr_src, dis, bufA);
  k_gemm<1><<<dim3(cdiv_h(EHd, 64), cdiv_h(Nn, 128)), 256, 0, stream>>>(
      bufB, EHd, Nn, hw2w, EHd, EHd, hw2b, bufA, EHd, x1, 600);

  // ---- gat_e (two calls) ----
  const int* eh = ei;
  const int* et = ei + Ee;
  float* xh = bufA;                    // relu(x @ wh.T)
  float* xt = bufA + (size_t)Nn * CHd; // relu(x @ wt.T)

  struct GP {
    const float* wh; const float* wt;
    const float* xm; const float* xo;
    const int* im; const int* io;
    const int* ci; const int* cls_ent;
    const float* ra1;
    const float* v2m; const float* v2o;
    const float* v3m; const float* v3o;
    const float* v4;  const float* acv;
    const float* hww; const float* hwb;
    float* x1out;
  };
  // call A: x_e_h (main_is_head = False): xm = x_t, xo = x_h
  GP A = { h2r_wh, h2r_wt, xt, xh, et, eh, cih, hcls, ra1h,
           h2r_ac + 5 * CHd, h2r_ac + 1 * CHd,
           h2r_ac + 6 * CHd, h2r_ac + 2 * CHd,
           h2r_ac + 3 * CHd, h2r_ac + 7 * CHd,
           h2r_hww, h2r_hwb, x1 + 300 };
  // call B: x_e_t (main_is_head = True): xm = x_h, xo = x_t
  GP B = { et_wh, et_wt, xh, xt, eh, et, cit, tcls, ra1e,
           et_ac + 1 * CHd, et_ac + 5 * CHd,
           et_ac + 2 * CHd, et_ac + 6 * CHd,
           et_ac + 3 * CHd, et_ac + 7 * CHd,
           et_hww, et_hwb, x1 + 450 };

  GP calls[2] = { A, B };
  for (int ci_ = 0; ci_ < 2; ci_++){
    const GP& P = calls[ci_];
    // x_h / x_t
    k_gemm<0><<<dim3(cdiv_h(CHd, 64), cdiv_h(Nn, 128)), 256, 0, stream>>>(
        x1, 600, Nn, P.wh, EHd, CHd, nullptr, nullptr, 0, xh, CHd);
    k_gemm<0><<<dim3(cdiv_h(CHd, 64), cdiv_h(Nn, 128)), 256, 0, stream>>>(
        x1, 600, Nn, P.wt, EHd, CHd, nullptr, nullptr, 0, xt, CHd);
    // init segment buffers
    hipMemsetAsync(csum, 0, Cc * 4, stream);
    hipMemsetAsync(x_class, 0, Cc * CHd * 4, stream);
    hipMemsetAsync(outb, 0, (size_t)Nn * CHd * 4, stream);
    k_fill<<<1, 256, 0, stream>>>(cmax, -INFINITY, Cc);
    // per-node precompute (xn, pm, po, nv4)
    k_ndots2<<<Nn, 64, 0, stream>>>(P.xm, P.xo, P.v2m, P.v3m, P.v2o, P.v3o, P.v4,
                                    xn, pm, po, nv4);
    // im2 = im[im]
    k_im2<<<cdiv_h(Ee, 256), 256, 0, stream>>>(P.im, im2);
    // per-edge logit + beta softmax
    k_e2<<<cdiv_h(Ee, 256), 256, 0, stream>>>(P.im, P.io, rel, P.ci, pm, po, P.ra1,
                                              es2, cmax);
    k_expsum<<<cdiv_h(Ee, 256), 256, 0, stream>>>(P.ci, cmax, es2, csum);
    // class aggregation
    k_xclass<<<cdiv_h(Ee, 4), 256, 0, stream>>>(im2, P.ci, es2, csum, xn, x_class);
    // e_c, gama, scatter
    k_classfinal<<<1, 256, 0, stream>>>(x_class, P.acv, nv4, P.cls_ent, outb);
    // final highway of this gat_e
    k_gemm<1><<<dim3(cdiv_h(CHd, 64), cdiv_h(Nn, 128)), 256, 0, stream>>>(
        P.xo, CHd, Nn, P.hww, CHd, CHd, P.hwb, outb, CHd, P.x1out, 600);
  }

  // ---- final GAT over x1 ----
  k_s12<<<Nn, 64, 0, stream>>>(x1, gai, gaj, s1v, s2v);
  k_gat<<<Nn, 256, 0, stream>>>(x1, csr_ptr, csr_src, s1v, s2v, out);
}

// Round 5
// 1090.536 us; speedup vs baseline: 1.8796x; 1.3464x over previous
//
#include <hip/hip_runtime.h>
#include <math.h>

#define Nn 20000
#define Ee 120000
#define EALLe 240000
#define Cc 150
#define Rr 1000
#define EHd 300
#define RHd 100
#define CHd 150
#define CB 64   // blocks for edge-pass kernels (per-thread ranks fit in 8)

static inline int cdiv_h(int a, int b){ return (a + b - 1) / b; }

__device__ __forceinline__ float lrelu01(float x){ return x > 0.f ? x : 0.01f * x; }

template<int Kq>
__device__ __forceinline__ void wredsumN(float* v){
#pragma unroll
  for (int m = 32; m >= 1; m >>= 1){
#pragma unroll
    for (int k = 0; k < Kq; k++) v[k] += __shfl_xor(v[k], m, 64);
  }
}

__global__ void k_fill(float* p, float v, int n){
  int i = blockIdx.x * blockDim.x + threadIdx.x;
  if (i < n) p[i] = v;
}

// normalize r_emb rows + the 2 live relation scalar tables (0.5 * r_emb_n @ ar[1])
__global__ __launch_bounds__(64) void k_rnorm(const float* __restrict__ rt,
    const float* __restrict__ arh, const float* __restrict__ are,
    float* __restrict__ ra1h, float* __restrict__ ra1e){
  int r = blockIdx.x, lane = threadIdx.x;
  bool m1 = (lane + 64 < RHd);
  float v0 = rt[r * RHd + lane];
  float v1 = m1 ? rt[r * RHd + lane + 64] : 0.f;
  float s[3];
  s[0] = v0 * v0 + v1 * v1;
  s[1] = v0 * arh[RHd + lane] + (m1 ? v1 * arh[RHd + lane + 64] : 0.f);
  s[2] = v0 * are[RHd + lane] + (m1 ? v1 * are[RHd + lane + 64] : 0.f);
  wredsumN<3>(s);
  float inv = 0.5f / fmaxf(sqrtf(s[0]), 1e-12f);   // fold the 0.5 factor of e_r
  if (!lane){
    ra1h[r] = s[1] * inv;
    ra1e[r] = s[2] * inv;
  }
}

__global__ void k_count(const int* __restrict__ dst, int* __restrict__ degi){
  int e = blockIdx.x * blockDim.x + threadIdx.x;
  if (e < EALLe) atomicAdd(&degi[dst[e]], 1);
}

__global__ void k_dis(const int* __restrict__ degi, float* __restrict__ dis){
  int n = blockIdx.x * blockDim.x + threadIdx.x;
  if (n < Nn) dis[n] = degi[n] > 0 ? rsqrtf((float)degi[n]) : 0.f;
}

// single-block exclusive scan of degi -> csr_ptr (and cursor copy)
__global__ __launch_bounds__(1024) void k_scan(const int* __restrict__ degi,
    int* __restrict__ ptr, int* __restrict__ cur){
  __shared__ int s[1024];
  int t = threadIdx.x;
  const int per = (Nn + 1023) / 1024;
  int b0 = t * per; if (b0 > Nn) b0 = Nn;
  int b1 = b0 + per; if (b1 > Nn) b1 = Nn;
  int sum = 0;
  for (int i = b0; i < b1; i++) sum += degi[i];
  s[t] = sum;
  __syncthreads();
  for (int off = 1; off < 1024; off <<= 1){
    int v = (t >= off) ? s[t - off] : 0;
    __syncthreads();
    s[t] += v;
    __syncthreads();
  }
  int run = (t > 0) ? s[t - 1] : 0;
  for (int i = b0; i < b1; i++){
    ptr[i] = run; cur[i] = run; run += degi[i];
  }
  if (t == 1023) ptr[Nn] = s[1023];
}

__global__ void k_scatter(const int* __restrict__ src, const int* __restrict__ dst,
    int* __restrict__ cur, int* __restrict__ csr_src){
  int e = blockIdx.x * blockDim.x + threadIdx.x;
  if (e >= EALLe) return;
  int pos = atomicAdd(&cur[dst[e]], 1);
  csr_src[pos] = src[e];
}

// GCN SpMM + relu: one wave per destination node
__global__ __launch_bounds__(64) void k_gcn(const float* __restrict__ x, int ldx,
    const int* __restrict__ ptr, const int* __restrict__ src,
    const float* __restrict__ dis, float* __restrict__ out){
  int i = blockIdx.x, lane = threadIdx.x;
  int p0 = ptr[i], p1 = ptr[i + 1];
  float di = dis[i];
  float a0 = 0.f, a1 = 0.f, a2 = 0.f, a3 = 0.f, a4 = 0.f;
  for (int k = p0; k < p1; k++){
    int j = src[k];
    float w = di * dis[j];
    const float* xr = x + (size_t)j * ldx;
    a0 += w * xr[lane];
    a1 += w * xr[lane + 64];
    a2 += w * xr[lane + 128];
    a3 += w * xr[lane + 192];
    if (lane < EHd - 256) a4 += w * xr[lane + 256];
  }
  float* orow = out + (size_t)i * EHd;
  orow[lane] = fmaxf(a0, 0.f);
  orow[lane + 64] = fmaxf(a1, 0.f);
  orow[lane + 128] = fmaxf(a2, 0.f);
  orow[lane + 192] = fmaxf(a3, 0.f);
  if (lane < EHd - 256) orow[lane + 256] = fmaxf(a4, 0.f);
}

// tiled f32 GEMM: out = epi( X[nrows,K] @ Wm[M,K]^T ). EPI 0=relu, 1=highway
// 128-row x 64-col block, 256 threads, 8x4 micro-tile, K-tile 16.
template<int EPI>
__global__ __launch_bounds__(256) void k_gemm(
    const float* __restrict__ X, int ldx, int nrows,
    const float* __restrict__ Wm, int K, int M,
    const float* __restrict__ bias,
    const float* __restrict__ X2, int ldx2,
    float* __restrict__ out, int ldo){
  __shared__ float Xs[16][132];
  __shared__ float Ws[16][68];
  int t = threadIdx.x;
  int c0 = blockIdx.x * 64, r0 = blockIdx.y * 128;
  int tx = t & 15, ty = t >> 4;          // micro-tile: rows ty*8..+7, cols tx*4..+3
  int lrow = t >> 2, lk = (t & 3) * 4;   // staging: 2 X-rows + 1 W-row, 4 k each
  int xr0 = r0 + lrow, xr1 = r0 + lrow + 64;
  int wr = c0 + lrow;
  const bool v4x = ((ldx & 3) == 0);
  const bool v4w = ((K & 3) == 0);
  float acc[8][4] = {};
  for (int k0 = 0; k0 < K; k0 += 16){
    bool kfull = (k0 + 16 <= K);
    float a0[4] = {0.f,0.f,0.f,0.f}, a1[4] = {0.f,0.f,0.f,0.f}, wv[4] = {0.f,0.f,0.f,0.f};
    if (kfull && v4x){
      if (xr0 < nrows) *(float4*)a0 = *(const float4*)&X[(size_t)xr0 * ldx + k0 + lk];
      if (xr1 < nrows) *(float4*)a1 = *(const float4*)&X[(size_t)xr1 * ldx + k0 + lk];
    } else {
#pragma unroll
      for (int q = 0; q < 4; q++){
        int kk = k0 + lk + q;
        if (kk < K){
          if (xr0 < nrows) a0[q] = X[(size_t)xr0 * ldx + kk];
          if (xr1 < nrows) a1[q] = X[(size_t)xr1 * ldx + kk];
        }
      }
    }
    if (kfull && v4w){
      if (wr < M) *(float4*)wv = *(const float4*)&Wm[(size_t)wr * K + k0 + lk];
    } else {
#pragma unroll
      for (int q = 0; q < 4; q++){
        int kk = k0 + lk + q;
        if (kk < K && wr < M) wv[q] = Wm[(size_t)wr * K + kk];
      }
    }
    __syncthreads();
#pragma unroll
    for (int q = 0; q < 4; q++){
      Xs[lk + q][lrow]      = a0[q];
      Xs[lk + q][lrow + 64] = a1[q];
      Ws[lk + q][lrow]      = wv[q];
    }
    __syncthreads();
#pragma unroll
    for (int kk = 0; kk < 16; kk++){
      float av[8], bv[4];
#pragma unroll
      for (int i = 0; i < 8; i++) av[i] = Xs[kk][ty * 8 + i];
#pragma unroll
      for (int j = 0; j < 4; j++) bv[j] = Ws[kk][tx * 4 + j];
#pragma unroll
      for (int i = 0; i < 8; i++)
#pragma unroll
        for (int j = 0; j < 4; j++) acc[i][j] += av[i] * bv[j];
    }
  }
#pragma unroll
  for (int i = 0; i < 8; i++){
    int r = r0 + ty * 8 + i;
    if (r >= nrows) continue;
#pragma unroll
    for (int j = 0; j < 4; j++){
      int c = c0 + tx * 4 + j;
      if (c >= M) continue;
      float v = acc[i][j];
      float o;
      if (EPI == 0){
        o = fmaxf(v, 0.f);
      } else {
        float g = 1.f / (1.f + expf(-(v + bias[c])));
        o = g * X2[(size_t)r * ldx2 + c] + (1.f - g) * X[(size_t)r * ldx + c];
      }
      out[(size_t)r * ldo + c] = o;
    }
  }
}

// per-node precompute for gat_e:
//   xn  = l2norm(xm_row); pm = xn.v2m + 0.25*xn.v3m; po = xo.v2o + 0.25*xo.v3o; nv4 = xo.v4
__global__ __launch_bounds__(64) void k_ndots2(
    const float* __restrict__ xm, const float* __restrict__ xo,
    const float* __restrict__ v2m, const float* __restrict__ v3m,
    const float* __restrict__ v2o, const float* __restrict__ v3o,
    const float* __restrict__ v4,
    float* __restrict__ xn, float* __restrict__ pm,
    float* __restrict__ po, float* __restrict__ nv4){
  int n = blockIdx.x, lane = threadIdx.x;
  bool m2 = lane < (CHd - 128);
  const float* mr = xm + (size_t)n * CHd;
  const float* orw = xo + (size_t)n * CHd;
  float m0 = mr[lane], m1 = mr[lane + 64], mv2 = m2 ? mr[lane + 128] : 0.f;
  float o0 = orw[lane], o1 = orw[lane + 64], o2 = m2 ? orw[lane + 128] : 0.f;
  float s[4];
  s[0] = m0 * m0 + m1 * m1 + mv2 * mv2;
  s[1] = o0 * v2o[lane] + o1 * v2o[lane + 64] + (m2 ? o2 * v2o[lane + 128] : 0.f);
  s[2] = o0 * v3o[lane] + o1 * v3o[lane + 64] + (m2 ? o2 * v3o[lane + 128] : 0.f);
  s[3] = o0 * v4[lane]  + o1 * v4[lane + 64]  + (m2 ? o2 * v4[lane + 128]  : 0.f);
  wredsumN<4>(s);
  float inv = 1.f / fmaxf(sqrtf(s[0]), 1e-12f);
  float n0 = m0 * inv, n1 = m1 * inv, n2 = mv2 * inv;
  float* xr = xn + (size_t)n * CHd;
  xr[lane] = n0; xr[lane + 64] = n1;
  if (m2) xr[lane + 128] = n2;
  float d[2];
  d[0] = n0 * v2m[lane] + n1 * v2m[lane + 64] + (m2 ? n2 * v2m[lane + 128] : 0.f);
  d[1] = n0 * v3m[lane] + n1 * v3m[lane + 64] + (m2 ? n2 * v3m[lane + 128] : 0.f);
  wredsumN<2>(d);
  if (!lane){
    pm[n] = d[0] + 0.25f * d[1];
    po[n] = s[1] + 0.25f * s[2];
    nv4[n] = s[3];
  }
}

// per-edge logit -> es2 = exp(lrelu(...)) (no max-shift; logits are O(1)),
// LDS-accumulated per-class sum + count, flushed to 64B-padded slots.
__global__ __launch_bounds__(256) void k_e2sum(
    const int* __restrict__ im, const int* __restrict__ io,
    const int* __restrict__ rel, const int* __restrict__ ci,
    const float* __restrict__ pm, const float* __restrict__ po,
    const float* __restrict__ ra1,
    float* __restrict__ es2, float* __restrict__ csum_p, int* __restrict__ ccnt_p){
  __shared__ float ls[Cc];
  __shared__ int lc[Cc];
  int t = threadIdx.x;
  for (int c = t; c < Cc; c += 256){ ls[c] = 0.f; lc[c] = 0; }
  __syncthreads();
  for (int e = blockIdx.x * 256 + t; e < Ee; e += gridDim.x * 256){
    float v = lrelu01(po[io[e]] + pm[im[e]] + ra1[rel[e]]);
    float s = expf(v);
    es2[e] = s;
    int c = ci[e];
    atomicAdd(&ls[c], s);
    atomicAdd(&lc[c], 1);
  }
  __syncthreads();
  for (int c = t; c < Cc; c += 256){
    if (lc[c]){
      atomicAdd(&csum_p[c * 16], ls[c]);
      atomicAdd(&ccnt_p[c * 16], lc[c]);
    }
  }
}

// tiny scan over 150 class counts -> cstart[151] and padded cursor copy
__global__ __launch_bounds__(256) void k_cscan(const int* __restrict__ ccnt_p,
    int* __restrict__ cstart, int* __restrict__ ccur_p){
  __shared__ int s[Cc + 1];
  int t = threadIdx.x;
  if (t == 0){
    int run = 0;
    for (int c = 0; c < Cc; c++){ s[c] = run; run += ccnt_p[c * 16]; }
    s[Cc] = run;
  }
  __syncthreads();
  if (t <= Cc) cstart[t] = s[t];
  if (t < Cc) ccur_p[t * 16] = s[t];
}

// two-level scatter into class-CSR: LDS local ranks, one block-base atomic per class.
// stores rows (im[im[e]]) and weights (es2[e]) directly.
__global__ __launch_bounds__(256) void k_cscatter(
    const int* __restrict__ ci, const int* __restrict__ im,
    const float* __restrict__ es2,
    int* __restrict__ ccur_p, int* __restrict__ crows, float* __restrict__ cw){
  __shared__ int lcnt[Cc];
  __shared__ int lbase[Cc];
  int t = threadIdx.x;
  int epb = (Ee + gridDim.x - 1) / gridDim.x;
  int e0 = blockIdx.x * epb, e1 = e0 + epb; if (e1 > Ee) e1 = Ee;
  for (int c = t; c < Cc; c += 256) lcnt[c] = 0;
  __syncthreads();
  int myr[8], myc[8], mye[8]; int cnt = 0;
  for (int e = e0 + t; e < e1; e += 256){
    int c = ci[e];
    myr[cnt] = atomicAdd(&lcnt[c], 1);
    myc[cnt] = c; mye[cnt] = e; cnt++;
  }
  __syncthreads();
  for (int c = t; c < Cc; c += 256)
    lbase[c] = lcnt[c] ? atomicAdd(&ccur_p[c * 16], lcnt[c]) : 0;
  __syncthreads();
  for (int q = 0; q < cnt; q++){
    int pos = lbase[myc[q]] + myr[q];
    int e = mye[q];
    crows[pos] = im[im[e]];   // literal x_edge[im] re-index
    cw[pos] = es2[e];
  }
}

// one block per class: x_class[c,:] = sum_e beta * xn[row], register accumulation
__global__ __launch_bounds__(192) void k_xclassB(
    const int* __restrict__ cstart, const int* __restrict__ crows,
    const float* __restrict__ cw, const float* __restrict__ csum_p,
    const float* __restrict__ xn, float* __restrict__ x_class){
  int c = blockIdx.x, t = threadIdx.x;
  int p0 = cstart[c], p1 = cstart[c + 1];
  bool act = t < CHd;
  float acc = 0.f;
  if (p1 > p0){
    float inv = 1.f / csum_p[c * 16];
    int k = p0;
    for (; k + 4 <= p1; k += 4){
      int r0 = crows[k], r1 = crows[k + 1], r2 = crows[k + 2], r3 = crows[k + 3];
      float w0 = cw[k] * inv, w1 = cw[k + 1] * inv, w2 = cw[k + 2] * inv, w3 = cw[k + 3] * inv;
      if (act){
        acc += w0 * xn[(size_t)r0 * CHd + t] + w1 * xn[(size_t)r1 * CHd + t]
             + w2 * xn[(size_t)r2 * CHd + t] + w3 * xn[(size_t)r3 * CHd + t];
      }
    }
    for (; k < p1; k++){
      if (act) acc += cw[k] * inv * xn[(size_t)crows[k] * CHd + t];
    }
  }
  if (act) x_class[c * CHd + t] = acc;
}

// single block: e_c, gama (segment softmax over cls_ent), scatter into outb
__global__ __launch_bounds__(256) void k_classfinal(
    const float* __restrict__ x_class, const float* __restrict__ acv,
    const float* __restrict__ nv4, const int* __restrict__ cls_ent,
    float* __restrict__ outb){
  __shared__ float v[Cc];
  __shared__ float g[Cc];
  __shared__ int ce[Cc];
  int t = threadIdx.x;
  if (t < Cc){
    ce[t] = cls_ent[t];
    float dot = 0.f;
    for (int f = 0; f < CHd; f++) dot += x_class[t * CHd + f] * acv[f];
    v[t] = lrelu01(dot + nv4[ce[t]]);
  }
  __syncthreads();
  if (t < Cc){
    int sgm = ce[t];
    float m = -3.0e38f;
    for (int c2 = 0; c2 < Cc; c2++) if (ce[c2] == sgm) m = fmaxf(m, v[c2]);
    float sum = 0.f;
    for (int c2 = 0; c2 < Cc; c2++) if (ce[c2] == sgm) sum += expf(v[c2] - m);
    g[t] = expf(v[t] - m) / sum;
  }
  __syncthreads();
  for (int idx = t; idx < Cc * CHd; idx += 256){
    int c = idx / CHd, f = idx - c * CHd;
    atomicAdd(&outb[(size_t)ce[c] * CHd + f], g[c] * x_class[c * CHd + f]);
  }
}

// per node dot of x1 row with gat_ai / gat_aj
__global__ __launch_bounds__(64) void k_s12(const float* __restrict__ x1,
    const float* __restrict__ ai, const float* __restrict__ aj,
    float* __restrict__ s1, float* __restrict__ s2){
  int n = blockIdx.x, lane = threadIdx.x;
  const float* xr = x1 + (size_t)n * 600;
  float sa = 0.f, sb = 0.f;
#pragma unroll
  for (int u = 0; u < 10; u++){
    int f = lane + u * 64;
    if (f < 600){
      float x = xr[f];
      sa += x * ai[f];
      sb += x * aj[f];
    }
  }
  float s[2] = { sa, sb };
  wredsumN<2>(s);
  if (!lane){ s1[n] = s[0]; s2[n] = s[1]; }
}

// final GAT over CSR + copy x into d_out[:, :300]
__global__ __launch_bounds__(256) void k_gat(const float* __restrict__ x1,
    const int* __restrict__ ptr, const int* __restrict__ src,
    const float* __restrict__ s1, const float* __restrict__ s2,
    float* __restrict__ dout){
  int i = blockIdx.x, t = threadIdx.x;
  float* orow = dout + (size_t)i * 900;
  const float* xi = x1 + (size_t)i * 600;
  for (int f = t; f < 300; f += 256) orow[f] = xi[f];
  int p0 = ptr[i], p1 = ptr[i + 1];
  if (p0 == p1){
    for (int f = t; f < 600; f += 256) orow[300 + f] = 0.f;
    return;
  }
  float s1i = s1[i];
  float m = -3.0e38f;
  for (int k = p0; k < p1; k++) m = fmaxf(m, lrelu01(s1i + s2[src[k]]));
  float acc0 = 0.f, acc1 = 0.f, acc2 = 0.f, den = 0.f;
  for (int k = p0; k < p1; k++){
    int j = src[k];
    float w = expf(lrelu01(s1i + s2[j]) - m);
    den += w;
    const float* xj = x1 + (size_t)j * 600;
    acc0 += w * xj[t];
    acc1 += w * xj[t + 256];
    if (t < 88) acc2 += w * xj[t + 512];
  }
  float invd = 1.f / den;
  orow[300 + t] = fmaxf(acc0 * invd, 0.f);
  orow[300 + t + 256] = fmaxf(acc1 * invd, 0.f);
  if (t < 88) orow[300 + t + 512] = fmaxf(acc2 * invd, 0.f);
}

extern "C" void kernel_launch(void* const* d_in, const int* in_sizes, int n_in,
                              void* d_out, int out_size, void* d_ws, size_t ws_size,
                              hipStream_t stream) {
  const float* x_e    = (const float*)d_in[0];
  const int*   ei     = (const int*)d_in[1];
  const int*   rel    = (const int*)d_in[2];
  const int*   eall   = (const int*)d_in[3];
  const int*   trip   = (const int*)d_in[4];
  const int*   cih    = (const int*)d_in[5];
  const int*   hcls   = (const int*)d_in[6];
  const int*   cit    = (const int*)d_in[7];
  const int*   tcls   = (const int*)d_in[8];
  const float* remb   = (const float*)d_in[9];
  const float* hw1w   = (const float*)d_in[10];
  const float* hw1b   = (const float*)d_in[11];
  const float* hw2w   = (const float*)d_in[12];
  const float* hw2b   = (const float*)d_in[13];
  const float* h2r_ac = (const float*)d_in[14];
  const float* h2r_ar = (const float*)d_in[15];
  const float* h2r_wh = (const float*)d_in[16];
  const float* h2r_wt = (const float*)d_in[17];
  const float* h2r_hww= (const float*)d_in[18];
  const float* h2r_hwb= (const float*)d_in[19];
  const float* et_ac  = (const float*)d_in[20];
  const float* et_ar  = (const float*)d_in[21];
  const float* et_wh  = (const float*)d_in[22];
  const float* et_wt  = (const float*)d_in[23];
  const float* et_hww = (const float*)d_in[24];
  const float* et_hwb = (const float*)d_in[25];
  const float* gai    = (const float*)d_in[26];
  const float* gaj    = (const float*)d_in[27];
  float* out = (float*)d_out;
  (void)trip;

  // ---- workspace allocator ----
  char* wsp = (char*)d_ws;
  auto alloc = [&](size_t nbytes) -> void* {
    void* p = (void*)wsp;
    wsp += (nbytes + 255) & ~(size_t)255;
    return p;
  };
  float* ra1h = (float*)alloc(Rr * 4);
  float* ra1e = (float*)alloc(Rr * 4);
  float* dis  = (float*)alloc(Nn * 4);
  int* degi    = (int*)alloc(Nn * 4);
  int* csr_ptr = (int*)alloc((Nn + 1) * 4);
  int* csr_cur = (int*)alloc(Nn * 4);
  int* csr_src = (int*)alloc((size_t)EALLe * 4);
  float* x1  = (float*)alloc((size_t)Nn * 600 * 4);
  float* xn  = (float*)alloc((size_t)Nn * CHd * 4);
  float* es2 = (float*)alloc((size_t)Ee * 4);
  float* pm  = (float*)alloc(Nn * 4);
  float* po  = (float*)alloc(Nn * 4);
  float* nv4 = (float*)alloc(Nn * 4);
  float* csum_p = (float*)alloc(Cc * 16 * 4);
  int*   ccnt_p = (int*)alloc(Cc * 16 * 4);
  int*   ccur_p = (int*)alloc(Cc * 16 * 4);
  int*   cstart = (int*)alloc((Cc + 1) * 4);
  int*   crows  = (int*)alloc((size_t)Ee * 4);
  float* cw     = (float*)alloc((size_t)Ee * 4);
  float* x_class = (float*)alloc(Cc * CHd * 4);
  float* s1v = (float*)alloc(Nn * 4);
  float* s2v = (float*)alloc(Nn * 4);

  // d_out doubles as scratch (fully rewritten by k_gat at the end)
  float* bufA = out;                      // N*300 floats
  float* bufB = out + (size_t)Nn * EHd;   // N*300 floats
  float* outb = bufB;                     // N*150 view for gat_e class scatter

  // ---- prologue: r_emb norm, degrees, CSR ----
  hipMemsetAsync(degi, 0, Nn * 4, stream);
  k_rnorm<<<Rr, 64, 0, stream>>>(remb, h2r_ar, et_ar, ra1h, ra1e);
  k_count<<<cdiv_h(EALLe, 256), 256, 0, stream>>>(eall + EALLe, degi);
  k_dis<<<cdiv_h(Nn, 256), 256, 0, stream>>>(degi, dis);
  k_scan<<<1, 1024, 0, stream>>>(degi, csr_ptr, csr_cur);
  k_scatter<<<cdiv_h(EALLe, 256), 256, 0, stream>>>(eall, eall + EALLe, csr_cur, csr_src);

  // ---- GCN + highway x2 ----
  k_gcn<<<Nn, 64, 0, stream>>>(x_e, EHd, csr_ptr, csr_src, dis, bufA);
  k_gemm<1><<<dim3(cdiv_h(EHd, 64), cdiv_h(Nn, 128)), 256, 0, stream>>>(
      x_e, EHd, Nn, hw1w, EHd, EHd, hw1b, bufA, EHd, bufB, EHd);
  k_gcn<<<Nn, 64, 0, stream>>>(bufB, EHd, csr_ptr, csr_src, dis, bufA);
  k_gemm<1><<<dim3(cdiv_h(EHd, 64), cdiv_h(Nn, 128)), 256, 0, stream>>>(
      bufB, EHd, Nn, hw2w, EHd, EHd, hw2b, bufA, EHd, x1, 600);

  // ---- gat_e (two calls) ----
  const int* eh = ei;
  const int* et = ei + Ee;
  float* xh = bufA;                    // relu(x @ wh.T)
  float* xt = bufA + (size_t)Nn * CHd; // relu(x @ wt.T)

  struct GP {
    const float* wh; const float* wt;
    const float* xm; const float* xo;
    const int* im; const int* io;
    const int* ci; const int* cls_ent;
    const float* ra1;
    const float* v2m; const float* v2o;
    const float* v3m; const float* v3o;
    const float* v4;  const float* acv;
    const float* hww; const float* hwb;
    float* x1out;
  };
  // call A: x_e_h (main_is_head = False): xm = x_t, xo = x_h
  GP A = { h2r_wh, h2r_wt, xt, xh, et, eh, cih, hcls, ra1h,
           h2r_ac + 5 * CHd, h2r_ac + 1 * CHd,
           h2r_ac + 6 * CHd, h2r_ac + 2 * CHd,
           h2r_ac + 3 * CHd, h2r_ac + 7 * CHd,
           h2r_hww, h2r_hwb, x1 + 300 };
  // call B: x_e_t (main_is_head = True): xm = x_h, xo = x_t
  GP B = { et_wh, et_wt, xh, xt, eh, et, cit, tcls, ra1e,
           et_ac + 1 * CHd, et_ac + 5 * CHd,
           et_ac + 2 * CHd, et_ac + 6 * CHd,
           et_ac + 3 * CHd, et_ac + 7 * CHd,
           et_hww, et_hwb, x1 + 450 };

  GP calls[2] = { A, B };
  for (int ci_ = 0; ci_ < 2; ci_++){
    const GP& P = calls[ci_];
    // x_h / x_t
    k_gemm<0><<<dim3(cdiv_h(CHd, 64), cdiv_h(Nn, 128)), 256, 0, stream>>>(
        x1, 600, Nn, P.wh, EHd, CHd, nullptr, nullptr, 0, xh, CHd);
    k_gemm<0><<<dim3(cdiv_h(CHd, 64), cdiv_h(Nn, 128)), 256, 0, stream>>>(
        x1, 600, Nn, P.wt, EHd, CHd, nullptr, nullptr, 0, xt, CHd);
    // init class-segment buffers (64B-padded slots)
    hipMemsetAsync(csum_p, 0, Cc * 16 * 4, stream);
    hipMemsetAsync(ccnt_p, 0, Cc * 16 * 4, stream);
    hipMemsetAsync(outb, 0, (size_t)Nn * CHd * 4, stream);
    // per-node precompute (xn, pm, po, nv4)
    k_ndots2<<<Nn, 64, 0, stream>>>(P.xm, P.xo, P.v2m, P.v3m, P.v2o, P.v3o, P.v4,
                                    xn, pm, po, nv4);
    // per-edge exp-logit + LDS-accumulated class sums/counts
    k_e2sum<<<CB, 256, 0, stream>>>(P.im, P.io, rel, P.ci, pm, po, P.ra1,
                                    es2, csum_p, ccnt_p);
    // class CSR: scan + two-level scatter
    k_cscan<<<1, 256, 0, stream>>>(ccnt_p, cstart, ccur_p);
    k_cscatter<<<CB, 256, 0, stream>>>(P.ci, P.im, es2, ccur_p, crows, cw);
    // per-class register accumulation of x_class
    k_xclassB<<<Cc, 192, 0, stream>>>(cstart, crows, cw, csum_p, xn, x_class);
    // e_c, gama, scatter
    k_classfinal<<<1, 256, 0, stream>>>(x_class, P.acv, nv4, P.cls_ent, outb);
    // final highway of this gat_e
    k_gemm<1><<<dim3(cdiv_h(CHd, 64), cdiv_h(Nn, 128)), 256, 0, stream>>>(
        P.xo, CHd, Nn, P.hww, CHd, CHd, P.hwb, outb, CHd, P.x1out, 600);
  }

  // ---- final GAT over x1 ----
  k_s12<<<Nn, 64, 0, stream>>>(x1, gai, gaj, s1v, s2v);
  k_gat<<<Nn, 256, 0, stream>>>(x1, csr_ptr, csr_src, s1v, s2v, out);
}

// Round 6
// 842.367 us; speedup vs baseline: 2.4334x; 1.2946x over previous
//
#include <hip/hip_runtime.h>
#include <math.h>

#define Nn 20000
#define Ee 120000
#define EALLe 240000
#define Cc 150
#define Rr 1000
#define EHd 300
#define RHd 100
#define CHd 150
#define CB 64

static inline int cdiv_h(int a, int b){ return (a + b - 1) / b; }

typedef __attribute__((ext_vector_type(8))) short short8;
typedef __attribute__((ext_vector_type(4))) float f32x4;

__device__ __forceinline__ float lrelu01(float x){ return x > 0.f ? x : 0.01f * x; }

__device__ __forceinline__ unsigned short f2b(float f){
  unsigned int u = __float_as_uint(f);
  unsigned int r = (u + 0x7FFFu + ((u >> 16) & 1u)) >> 16;
  return (unsigned short)r;
}

template<int Kq>
__device__ __forceinline__ void wredsumN(float* v){
#pragma unroll
  for (int m = 32; m >= 1; m >>= 1){
#pragma unroll
    for (int k = 0; k < Kq; k++) v[k] += __shfl_xor(v[k], m, 64);
  }
}

// f32 [rows, ncols] (ld ldsrc) -> bf16 [rows, ldp], zero-padded cols ncols..ldp
__global__ __launch_bounds__(64) void k_f2b(const float* __restrict__ src, int ncols,
    int ldsrc, unsigned short* __restrict__ dst, int ldp){
  int r = blockIdx.x, t = threadIdx.x;
  for (int c = t; c < ldp; c += 64)
    dst[(size_t)r * ldp + c] = (c < ncols) ? f2b(src[(size_t)r * ldsrc + c]) : (unsigned short)0;
}

// normalize r_emb rows + the 2 live relation scalar tables (0.5 * r_emb_n @ ar[1])
__global__ __launch_bounds__(64) void k_rnorm(const float* __restrict__ rt,
    const float* __restrict__ arh, const float* __restrict__ are,
    float* __restrict__ ra1h, float* __restrict__ ra1e){
  int r = blockIdx.x, lane = threadIdx.x;
  bool m1 = (lane + 64 < RHd);
  float v0 = rt[r * RHd + lane];
  float v1 = m1 ? rt[r * RHd + lane + 64] : 0.f;
  float s[3];
  s[0] = v0 * v0 + v1 * v1;
  s[1] = v0 * arh[RHd + lane] + (m1 ? v1 * arh[RHd + lane + 64] : 0.f);
  s[2] = v0 * are[RHd + lane] + (m1 ? v1 * are[RHd + lane + 64] : 0.f);
  wredsumN<3>(s);
  float inv = 0.5f / fmaxf(sqrtf(s[0]), 1e-12f);
  if (!lane){
    ra1h[r] = s[1] * inv;
    ra1e[r] = s[2] * inv;
  }
}

__global__ void k_count(const int* __restrict__ dst, int* __restrict__ degi){
  int e = blockIdx.x * blockDim.x + threadIdx.x;
  if (e < EALLe) atomicAdd(&degi[dst[e]], 1);
}

__global__ void k_dis(const int* __restrict__ degi, float* __restrict__ dis){
  int n = blockIdx.x * blockDim.x + threadIdx.x;
  if (n < Nn) dis[n] = degi[n] > 0 ? rsqrtf((float)degi[n]) : 0.f;
}

__global__ __launch_bounds__(1024) void k_scan(const int* __restrict__ degi,
    int* __restrict__ ptr, int* __restrict__ cur){
  __shared__ int s[1024];
  int t = threadIdx.x;
  const int per = (Nn + 1023) / 1024;
  int b0 = t * per; if (b0 > Nn) b0 = Nn;
  int b1 = b0 + per; if (b1 > Nn) b1 = Nn;
  int sum = 0;
  for (int i = b0; i < b1; i++) sum += degi[i];
  s[t] = sum;
  __syncthreads();
  for (int off = 1; off < 1024; off <<= 1){
    int v = (t >= off) ? s[t - off] : 0;
    __syncthreads();
    s[t] += v;
    __syncthreads();
  }
  int run = (t > 0) ? s[t - 1] : 0;
  for (int i = b0; i < b1; i++){
    ptr[i] = run; cur[i] = run; run += degi[i];
  }
  if (t == 1023) ptr[Nn] = s[1023];
}

__global__ void k_scatter(const int* __restrict__ src, const int* __restrict__ dst,
    int* __restrict__ cur, int* __restrict__ csr_src){
  int e = blockIdx.x * blockDim.x + threadIdx.x;
  if (e >= EALLe) return;
  int pos = atomicAdd(&cur[dst[e]], 1);
  csr_src[pos] = src[e];
}

// GCN SpMM + relu: one wave per destination node
__global__ __launch_bounds__(64) void k_gcn(const float* __restrict__ x, int ldx,
    const int* __restrict__ ptr, const int* __restrict__ src,
    const float* __restrict__ dis, float* __restrict__ out){
  int i = blockIdx.x, lane = threadIdx.x;
  int p0 = ptr[i], p1 = ptr[i + 1];
  float di = dis[i];
  float a0 = 0.f, a1 = 0.f, a2 = 0.f, a3 = 0.f, a4 = 0.f;
  for (int k = p0; k < p1; k++){
    int j = src[k];
    float w = di * dis[j];
    const float* xr = x + (size_t)j * ldx;
    a0 += w * xr[lane];
    a1 += w * xr[lane + 64];
    a2 += w * xr[lane + 128];
    a3 += w * xr[lane + 192];
    if (lane < EHd - 256) a4 += w * xr[lane + 256];
  }
  float* orow = out + (size_t)i * EHd;
  orow[lane] = fmaxf(a0, 0.f);
  orow[lane + 64] = fmaxf(a1, 0.f);
  orow[lane + 128] = fmaxf(a2, 0.f);
  orow[lane + 192] = fmaxf(a3, 0.f);
  if (lane < EHd - 256) orow[lane + 256] = fmaxf(a4, 0.f);
}

// bf16 MFMA GEMM: out = epi( Xb[nrows,Kp]bf16 @ Wb[M,Kp]bf16^T ).
// 64x64 tile, 4 waves, mfma_f32_16x16x32_bf16. EPI 0=relu, 1=highway.
// MIR=1: also write bf16 copy of the output (for chained GEMMs). W K-pad rows are
// exact zeros (k_f2b), so garbage in X pad cols contributes 0.
template<int EPI, int MIR>
__global__ __launch_bounds__(256) void k_gemmb(
    const unsigned short* __restrict__ Xb, int ldxb, int nrows,
    const unsigned short* __restrict__ Wb, int Kp, int M,
    const float* __restrict__ bias,
    const float* __restrict__ X2, int ldx2,
    const float* __restrict__ Xf, int ldxf,
    float* __restrict__ out, int ldo,
    unsigned short* __restrict__ mir, int ldmir){
  __shared__ unsigned short Xs[64][40];
  __shared__ unsigned short Ws[64][40];
  int t = threadIdx.x;
  int wv = t >> 6, lane = t & 63;
  int c0 = blockIdx.x * 64, r0 = blockIdx.y * 64;
  int srow = t >> 2, skoff = (t & 3) * 8;    // staging: row, 8-bf16 chunk
  int gxr = r0 + srow, gwr = c0 + srow;
  f32x4 acc[4] = {};
  for (int k0 = 0; k0 < Kp; k0 += 32){
    short8 xv = {0,0,0,0,0,0,0,0};
    short8 wv8 = {0,0,0,0,0,0,0,0};
    if (gxr < nrows) xv = *(const short8*)&Xb[(size_t)gxr * ldxb + k0 + skoff];
    if (gwr < M)     wv8 = *(const short8*)&Wb[(size_t)gwr * Kp + k0 + skoff];
    __syncthreads();
    *(short8*)&Xs[srow][skoff] = xv;
    *(short8*)&Ws[srow][skoff] = wv8;
    __syncthreads();
    int arow = wv * 16 + (lane & 15);
    int kk = (lane >> 4) * 8;
    short8 af = *(const short8*)&Xs[arow][kk];
#pragma unroll
    for (int j = 0; j < 4; j++){
      short8 bf = *(const short8*)&Ws[j * 16 + (lane & 15)][kk];
      acc[j] = __builtin_amdgcn_mfma_f32_16x16x32_bf16(af, bf, acc[j], 0, 0, 0);
    }
  }
  // C/D layout (m89-verified): col = lane&15, row = (lane>>4)*4 + reg
  int rbase = r0 + wv * 16 + (lane >> 4) * 4;
  int cbase = c0 + (lane & 15);
#pragma unroll
  for (int j = 0; j < 4; j++){
    int c = cbase + j * 16;
    if (c >= M) continue;
#pragma unroll
    for (int r = 0; r < 4; r++){
      int row = rbase + r;
      if (row >= nrows) continue;
      float v = acc[j][r];
      float o;
      if (EPI == 0){
        o = fmaxf(v, 0.f);
      } else {
        float g = 1.f / (1.f + expf(-(v + bias[c])));
        o = g * X2[(size_t)row * ldx2 + c] + (1.f - g) * Xf[(size_t)row * ldxf + c];
      }
      out[(size_t)row * ldo + c] = o;
      if (MIR) mir[(size_t)row * ldmir + c] = f2b(o);
    }
  }
}

// per-node precompute for gat_e (xm/xo live in proj with ld 600)
__global__ __launch_bounds__(64) void k_ndots2(
    const float* __restrict__ xm, const float* __restrict__ xo, int ldp,
    const float* __restrict__ v2m, const float* __restrict__ v3m,
    const float* __restrict__ v2o, const float* __restrict__ v3o,
    const float* __restrict__ v4,
    float* __restrict__ xn, float* __restrict__ pm,
    float* __restrict__ po, float* __restrict__ nv4){
  int n = blockIdx.x, lane = threadIdx.x;
  bool m2 = lane < (CHd - 128);
  const float* mr = xm + (size_t)n * ldp;
  const float* orw = xo + (size_t)n * ldp;
  float m0 = mr[lane], m1 = mr[lane + 64], mv2 = m2 ? mr[lane + 128] : 0.f;
  float o0 = orw[lane], o1 = orw[lane + 64], o2 = m2 ? orw[lane + 128] : 0.f;
  float s[4];
  s[0] = m0 * m0 + m1 * m1 + mv2 * mv2;
  s[1] = o0 * v2o[lane] + o1 * v2o[lane + 64] + (m2 ? o2 * v2o[lane + 128] : 0.f);
  s[2] = o0 * v3o[lane] + o1 * v3o[lane + 64] + (m2 ? o2 * v3o[lane + 128] : 0.f);
  s[3] = o0 * v4[lane]  + o1 * v4[lane + 64]  + (m2 ? o2 * v4[lane + 128]  : 0.f);
  wredsumN<4>(s);
  float inv = 1.f / fmaxf(sqrtf(s[0]), 1e-12f);
  float n0 = m0 * inv, n1 = m1 * inv, n2 = mv2 * inv;
  float* xr = xn + (size_t)n * CHd;
  xr[lane] = n0; xr[lane + 64] = n1;
  if (m2) xr[lane + 128] = n2;
  float d[2];
  d[0] = n0 * v2m[lane] + n1 * v2m[lane + 64] + (m2 ? n2 * v2m[lane + 128] : 0.f);
  d[1] = n0 * v3m[lane] + n1 * v3m[lane + 64] + (m2 ? n2 * v3m[lane + 128] : 0.f);
  wredsumN<2>(d);
  if (!lane){
    pm[n] = d[0] + 0.25f * d[1];
    po[n] = s[1] + 0.25f * s[2];
    nv4[n] = s[3];
  }
}

// per-edge exp-logit (no max-shift; logits O(1)), LDS class sums/counts -> padded slots
__global__ __launch_bounds__(256) void k_e2sum(
    const int* __restrict__ im, const int* __restrict__ io,
    const int* __restrict__ rel, const int* __restrict__ ci,
    const float* __restrict__ pm, const float* __restrict__ po,
    const float* __restrict__ ra1,
    float* __restrict__ es2, float* __restrict__ csum_p, int* __restrict__ ccnt_p){
  __shared__ float ls[Cc];
  __shared__ int lc[Cc];
  int t = threadIdx.x;
  for (int c = t; c < Cc; c += 256){ ls[c] = 0.f; lc[c] = 0; }
  __syncthreads();
  for (int e = blockIdx.x * 256 + t; e < Ee; e += gridDim.x * 256){
    float v = lrelu01(po[io[e]] + pm[im[e]] + ra1[rel[e]]);
    float s = expf(v);
    es2[e] = s;
    int c = ci[e];
    atomicAdd(&ls[c], s);
    atomicAdd(&lc[c], 1);
  }
  __syncthreads();
  for (int c = t; c < Cc; c += 256){
    if (lc[c]){
      atomicAdd(&csum_p[c * 16], ls[c]);
      atomicAdd(&ccnt_p[c * 16], lc[c]);
    }
  }
}

__global__ __launch_bounds__(256) void k_cscan(const int* __restrict__ ccnt_p,
    int* __restrict__ cstart, int* __restrict__ ccur_p){
  __shared__ int s[Cc + 1];
  int t = threadIdx.x;
  if (t == 0){
    int run = 0;
    for (int c = 0; c < Cc; c++){ s[c] = run; run += ccnt_p[c * 16]; }
    s[Cc] = run;
  }
  __syncthreads();
  if (t <= Cc) cstart[t] = s[t];
  if (t < Cc) ccur_p[t * 16] = s[t];
}

__global__ __launch_bounds__(256) void k_cscatter(
    const int* __restrict__ ci, const int* __restrict__ im,
    const float* __restrict__ es2,
    int* __restrict__ ccur_p, int* __restrict__ crows, float* __restrict__ cw){
  __shared__ int lcnt[Cc];
  __shared__ int lbase[Cc];
  int t = threadIdx.x;
  int epb = (Ee + gridDim.x - 1) / gridDim.x;
  int e0 = blockIdx.x * epb, e1 = e0 + epb; if (e1 > Ee) e1 = Ee;
  for (int c = t; c < Cc; c += 256) lcnt[c] = 0;
  __syncthreads();
  int myr[8], myc[8], mye[8]; int cnt = 0;
  for (int e = e0 + t; e < e1; e += 256){
    int c = ci[e];
    myr[cnt] = atomicAdd(&lcnt[c], 1);
    myc[cnt] = c; mye[cnt] = e; cnt++;
  }
  __syncthreads();
  for (int c = t; c < Cc; c += 256)
    lbase[c] = lcnt[c] ? atomicAdd(&ccur_p[c * 16], lcnt[c]) : 0;
  __syncthreads();
  for (int q = 0; q < cnt; q++){
    int pos = lbase[myc[q]] + myr[q];
    int e = mye[q];
    crows[pos] = im[im[e]];
    cw[pos] = es2[e];
  }
}

__global__ __launch_bounds__(192) void k_xclassB(
    const int* __restrict__ cstart, const int* __restrict__ crows,
    const float* __restrict__ cw, const float* __restrict__ csum_p,
    const float* __restrict__ xn, float* __restrict__ x_class){
  int c = blockIdx.x, t = threadIdx.x;
  int p0 = cstart[c], p1 = cstart[c + 1];
  bool act = t < CHd;
  float acc = 0.f;
  if (p1 > p0){
    float inv = 1.f / csum_p[c * 16];
    int k = p0;
    for (; k + 4 <= p1; k += 4){
      int r0 = crows[k], r1 = crows[k + 1], r2 = crows[k + 2], r3 = crows[k + 3];
      float w0 = cw[k] * inv, w1 = cw[k + 1] * inv, w2 = cw[k + 2] * inv, w3 = cw[k + 3] * inv;
      if (act){
        acc += w0 * xn[(size_t)r0 * CHd + t] + w1 * xn[(size_t)r1 * CHd + t]
             + w2 * xn[(size_t)r2 * CHd + t] + w3 * xn[(size_t)r3 * CHd + t];
      }
    }
    for (; k < p1; k++){
      if (act) acc += cw[k] * inv * xn[(size_t)crows[k] * CHd + t];
    }
  }
  if (act) x_class[c * CHd + t] = acc;
}

__global__ __launch_bounds__(256) void k_classfinal(
    const float* __restrict__ x_class, const float* __restrict__ acv,
    const float* __restrict__ nv4, const int* __restrict__ cls_ent,
    float* __restrict__ outb){
  __shared__ float v[Cc];
  __shared__ float g[Cc];
  __shared__ int ce[Cc];
  int t = threadIdx.x;
  if (t < Cc){
    ce[t] = cls_ent[t];
    float dot = 0.f;
    for (int f = 0; f < CHd; f++) dot += x_class[t * CHd + f] * acv[f];
    v[t] = lrelu01(dot + nv4[ce[t]]);
  }
  __syncthreads();
  if (t < Cc){
    int sgm = ce[t];
    float m = -3.0e38f;
    for (int c2 = 0; c2 < Cc; c2++) if (ce[c2] == sgm) m = fmaxf(m, v[c2]);
    float sum = 0.f;
    for (int c2 = 0; c2 < Cc; c2++) if (ce[c2] == sgm) sum += expf(v[c2] - m);
    g[t] = expf(v[t] - m) / sum;
  }
  __syncthreads();
  for (int idx = t; idx < Cc * CHd; idx += 256){
    int c = idx / CHd, f = idx - c * CHd;
    atomicAdd(&outb[(size_t)ce[c] * CHd + f], g[c] * x_class[c * CHd + f]);
  }
}

__global__ __launch_bounds__(64) void k_s12(const float* __restrict__ x1,
    const float* __restrict__ ai, const float* __restrict__ aj,
    float* __restrict__ s1, float* __restrict__ s2){
  int n = blockIdx.x, lane = threadIdx.x;
  const float* xr = x1 + (size_t)n * 600;
  float sa = 0.f, sb = 0.f;
#pragma unroll
  for (int u = 0; u < 10; u++){
    int f = lane + u * 64;
    if (f < 600){
      float x = xr[f];
      sa += x * ai[f];
      sb += x * aj[f];
    }
  }
  float s[2] = { sa, sb };
  wredsumN<2>(s);
  if (!lane){ s1[n] = s[0]; s2[n] = s[1]; }
}

// final GAT over CSR (single pass, no max-shift) + copy x into d_out[:, :300]
__global__ __launch_bounds__(256) void k_gat(const float* __restrict__ x1,
    const int* __restrict__ ptr, const int* __restrict__ src,
    const float* __restrict__ s1, const float* __restrict__ s2,
    float* __restrict__ dout){
  int i = blockIdx.x, t = threadIdx.x;
  float* orow = dout + (size_t)i * 900;
  const float* xi = x1 + (size_t)i * 600;
  for (int f = t; f < 300; f += 256) orow[f] = xi[f];
  int p0 = ptr[i], p1 = ptr[i + 1];
  if (p0 == p1){
    for (int f = t; f < 600; f += 256) orow[300 + f] = 0.f;
    return;
  }
  float s1i = s1[i];
  float acc0 = 0.f, acc1 = 0.f, acc2 = 0.f, den = 0.f;
  for (int k = p0; k < p1; k++){
    int j = src[k];
    float w = expf(lrelu01(s1i + s2[j]));
    den += w;
    const float* xj = x1 + (size_t)j * 600;
    acc0 += w * xj[t];
    acc1 += w * xj[t + 256];
    if (t < 88) acc2 += w * xj[t + 512];
  }
  float invd = 1.f / den;
  orow[300 + t] = fmaxf(acc0 * invd, 0.f);
  orow[300 + t + 256] = fmaxf(acc1 * invd, 0.f);
  if (t < 88) orow[300 + t + 512] = fmaxf(acc2 * invd, 0.f);
}

extern "C" void kernel_launch(void* const* d_in, const int* in_sizes, int n_in,
                              void* d_out, int out_size, void* d_ws, size_t ws_size,
                              hipStream_t stream) {
  const float* x_e    = (const float*)d_in[0];
  const int*   ei     = (const int*)d_in[1];
  const int*   rel    = (const int*)d_in[2];
  const int*   eall   = (const int*)d_in[3];
  const int*   cih    = (const int*)d_in[5];
  const int*   hcls   = (const int*)d_in[6];
  const int*   cit    = (const int*)d_in[7];
  const int*   tcls   = (const int*)d_in[8];
  const float* remb   = (const float*)d_in[9];
  const float* hw1w   = (const float*)d_in[10];
  const float* hw1b   = (const float*)d_in[11];
  const float* hw2w   = (const float*)d_in[12];
  const float* hw2b   = (const float*)d_in[13];
  const float* h2r_ac = (const float*)d_in[14];
  const float* h2r_ar = (const float*)d_in[15];
  const float* h2r_wh = (const float*)d_in[16];
  const float* h2r_wt = (const float*)d_in[17];
  const float* h2r_hww= (const float*)d_in[18];
  const float* h2r_hwb= (const float*)d_in[19];
  const float* et_ac  = (const float*)d_in[20];
  const float* et_ar  = (const float*)d_in[21];
  const float* et_wh  = (const float*)d_in[22];
  const float* et_wt  = (const float*)d_in[23];
  const float* et_hww = (const float*)d_in[24];
  const float* et_hwb = (const float*)d_in[25];
  const float* gai    = (const float*)d_in[26];
  const float* gaj    = (const float*)d_in[27];
  float* out = (float*)d_out;

  // ---- workspace allocator ----
  char* wsp = (char*)d_ws;
  auto alloc = [&](size_t nbytes) -> void* {
    void* p = (void*)wsp;
    wsp += (nbytes + 255) & ~(size_t)255;
    return p;
  };
  float* ra1h = (float*)alloc(Rr * 4);
  float* ra1e = (float*)alloc(Rr * 4);
  float* dis  = (float*)alloc(Nn * 4);
  int* degi    = (int*)alloc(Nn * 4);
  int* csr_ptr = (int*)alloc((Nn + 1) * 4);
  int* csr_cur = (int*)alloc(Nn * 4);
  int* csr_src = (int*)alloc((size_t)EALLe * 4);
  float* x1  = (float*)alloc((size_t)Nn * 600 * 4);
  float* xn  = (float*)alloc((size_t)Nn * CHd * 4);
  float* es2 = (float*)alloc((size_t)Ee * 4);
  float* pm  = (float*)alloc(Nn * 4);
  float* po  = (float*)alloc(Nn * 4);
  float* nv4 = (float*)alloc(Nn * 4);
  float* csum_p = (float*)alloc(Cc * 16 * 4);
  int*   ccnt_p = (int*)alloc(Cc * 16 * 4);
  int*   ccur_p = (int*)alloc(Cc * 16 * 4);
  int*   cstart = (int*)alloc((Cc + 1) * 4);
  int*   crows  = (int*)alloc((size_t)Ee * 4);
  float* cw     = (float*)alloc((size_t)Ee * 4);
  float* x_class = (float*)alloc(Cc * CHd * 4);
  float* s1v = (float*)alloc(Nn * 4);
  float* s2v = (float*)alloc(Nn * 4);
  // bf16 arenas
  unsigned short* arenaA = (unsigned short*)alloc((size_t)Nn * 320 * 2);
  unsigned short* arenaB = (unsigned short*)alloc((size_t)Nn * 320 * 2);
  unsigned short* xob    = (unsigned short*)alloc((size_t)Nn * 160 * 2);
  unsigned short* w1b    = (unsigned short*)alloc((size_t)300 * 320 * 2);
  unsigned short* w2b    = (unsigned short*)alloc((size_t)300 * 320 * 2);
  unsigned short* wcatb  = (unsigned short*)alloc((size_t)600 * 320 * 2);
  unsigned short* hwwbA  = (unsigned short*)alloc((size_t)150 * 160 * 2);
  unsigned short* hwwbB  = (unsigned short*)alloc((size_t)150 * 160 * 2);

  // d_out staging layout (all dead before k_gat rewrites d_out):
  //   phase 1: h1 = out[0..300N), gbuf = out[300N..600N)
  //   phase 2: proj = out[0..600N) (4 x-projections), outb = out[600N..750N)
  float* h1   = out;
  float* gbuf = out + (size_t)Nn * EHd;
  float* proj = out;
  float* outb = out + (size_t)Nn * 600;

  // ---- prologue: r_emb norm, degrees, CSR, weight conversions ----
  hipMemsetAsync(degi, 0, Nn * 4, stream);
  k_rnorm<<<Rr, 64, 0, stream>>>(remb, h2r_ar, et_ar, ra1h, ra1e);
  k_count<<<cdiv_h(EALLe, 256), 256, 0, stream>>>(eall + EALLe, degi);
  k_dis<<<cdiv_h(Nn, 256), 256, 0, stream>>>(degi, dis);
  k_scan<<<1, 1024, 0, stream>>>(degi, csr_ptr, csr_cur);
  k_scatter<<<cdiv_h(EALLe, 256), 256, 0, stream>>>(eall, eall + EALLe, csr_cur, csr_src);
  k_f2b<<<300, 64, 0, stream>>>(hw1w, 300, 300, w1b, 320);
  k_f2b<<<300, 64, 0, stream>>>(hw2w, 300, 300, w2b, 320);
  k_f2b<<<150, 64, 0, stream>>>(h2r_wh, 300, 300, wcatb + (size_t)0   * 320, 320);
  k_f2b<<<150, 64, 0, stream>>>(h2r_wt, 300, 300, wcatb + (size_t)150 * 320, 320);
  k_f2b<<<150, 64, 0, stream>>>(et_wh,  300, 300, wcatb + (size_t)300 * 320, 320);
  k_f2b<<<150, 64, 0, stream>>>(et_wt,  300, 300, wcatb + (size_t)450 * 320, 320);
  k_f2b<<<150, 64, 0, stream>>>(h2r_hww, 150, 150, hwwbA, 160);
  k_f2b<<<150, 64, 0, stream>>>(et_hww,  150, 150, hwwbB, 160);
  k_f2b<<<Nn, 64, 0, stream>>>(x_e, 300, 300, arenaA, 320);

  // ---- GCN + highway x2 (bf16 MFMA GEMMs, mirror-chained) ----
  k_gcn<<<Nn, 64, 0, stream>>>(x_e, EHd, csr_ptr, csr_src, dis, gbuf);
  k_gemmb<1,1><<<dim3(5, cdiv_h(Nn, 64)), 256, 0, stream>>>(
      arenaA, 320, Nn, w1b, 320, 300, hw1b, gbuf, 300, x_e, 300, h1, 300, arenaB, 320);
  k_gcn<<<Nn, 64, 0, stream>>>(h1, EHd, csr_ptr, csr_src, dis, gbuf);
  k_gemmb<1,1><<<dim3(5, cdiv_h(Nn, 64)), 256, 0, stream>>>(
      arenaB, 320, Nn, w2b, 320, 300, hw2b, gbuf, 300, h1, 300, x1, 600, arenaA, 320);

  // ---- batched projections: [xh_A | xt_A | xh_B | xt_B] = relu(x @ wcat^T) ----
  // (overwrites h1/gbuf region of d_out — both dead)
  k_gemmb<0,0><<<dim3(10, cdiv_h(Nn, 64)), 256, 0, stream>>>(
      arenaA, 320, Nn, wcatb, 320, 600, nullptr, nullptr, 0, nullptr, 0, proj, 600,
      nullptr, 0);

  // ---- gat_e (two calls) ----
  struct GP {
    const float* xm; const float* xo;
    const int* im; const int* io;
    const int* ci; const int* cls_ent;
    const float* ra1;
    const float* v2m; const float* v2o;
    const float* v3m; const float* v3o;
    const float* v4;  const float* acv;
    const unsigned short* hwwb; const float* hwb;
    float* x1out;
  };
  const int* eh = ei;
  const int* et = ei + Ee;
  // call A: x_e_h (main_is_head=False): xm = x_t(A) = proj+150, xo = x_h(A) = proj+0
  GP A = { proj + 150, proj + 0, et, eh, cih, hcls, ra1h,
           h2r_ac + 5 * CHd, h2r_ac + 1 * CHd,
           h2r_ac + 6 * CHd, h2r_ac + 2 * CHd,
           h2r_ac + 3 * CHd, h2r_ac + 7 * CHd,
           hwwbA, h2r_hwb, x1 + 300 };
  // call B: x_e_t (main_is_head=True): xm = x_h(B) = proj+300, xo = x_t(B) = proj+450
  GP B = { proj + 300, proj + 450, eh, et, cit, tcls, ra1e,
           et_ac + 1 * CHd, et_ac + 5 * CHd,
           et_ac + 2 * CHd, et_ac + 6 * CHd,
           et_ac + 3 * CHd, et_ac + 7 * CHd,
           hwwbB, et_hwb, x1 + 450 };

  GP calls[2] = { A, B };
  for (int ci_ = 0; ci_ < 2; ci_++){
    const GP& P = calls[ci_];
    hipMemsetAsync(csum_p, 0, Cc * 16 * 4, stream);
    hipMemsetAsync(ccnt_p, 0, Cc * 16 * 4, stream);
    hipMemsetAsync(outb, 0, (size_t)Nn * CHd * 4, stream);
    k_ndots2<<<Nn, 64, 0, stream>>>(P.xm, P.xo, 600, P.v2m, P.v3m, P.v2o, P.v3o, P.v4,
                                    xn, pm, po, nv4);
    k_e2sum<<<CB, 256, 0, stream>>>(P.im, P.io, rel, P.ci, pm, po, P.ra1,
                                    es2, csum_p, ccnt_p);
    k_cscan<<<1, 256, 0, stream>>>(ccnt_p, cstart, ccur_p);
    k_cscatter<<<CB, 256, 0, stream>>>(P.ci, P.im, es2, ccur_p, crows, cw);
    k_xclassB<<<Cc, 192, 0, stream>>>(cstart, crows, cw, csum_p, xn, x_class);
    k_classfinal<<<1, 256, 0, stream>>>(x_class, P.acv, nv4, P.cls_ent, outb);
    // highway(xo, outb) via bf16 GEMM: convert xo slice then gemm
    k_f2b<<<Nn, 64, 0, stream>>>(P.xo, 150, 600, xob, 160);
    k_gemmb<1,0><<<dim3(3, cdiv_h(Nn, 64)), 256, 0, stream>>>(
        xob, 160, Nn, P.hwwb, 160, 150, P.hwb, outb, 150, P.xo, 600, P.x1out, 600,
        nullptr, 0);
  }

  // ---- final GAT over x1 ----
  k_s12<<<Nn, 64, 0, stream>>>(x1, gai, gaj, s1v, s2v);
  k_gat<<<Nn, 256, 0, stream>>>(x1, csr_ptr, csr_src, s1v, s2v, out);
}

// Round 7
// 802.933 us; speedup vs baseline: 2.5529x; 1.0491x over previous
//
#include <hip/hip_runtime.h>
#include <math.h>

#define Nn 20000
#define Ee 120000
#define EALLe 240000
#define Cc 150
#define Rr 1000
#define EHd 300
#define RHd 100
#define CHd 150
#define CB 64

static inline int cdiv_h(int a, int b){ return (a + b - 1) / b; }

typedef __attribute__((ext_vector_type(8))) short short8;
typedef __attribute__((ext_vector_type(4))) float f32x4;

__device__ __forceinline__ float lrelu01(float x){ return x > 0.f ? x : 0.01f * x; }

__device__ __forceinline__ unsigned short f2b(float f){
  unsigned int u = __float_as_uint(f);
  unsigned int r = (u + 0x7FFFu + ((u >> 16) & 1u)) >> 16;
  return (unsigned short)r;
}
__device__ __forceinline__ float b2f(unsigned short u){
  return __uint_as_float(((unsigned int)u) << 16);
}

template<int Kq>
__device__ __forceinline__ void wredsumN(float* v){
#pragma unroll
  for (int m = 32; m >= 1; m >>= 1){
#pragma unroll
    for (int k = 0; k < Kq; k++) v[k] += __shfl_xor(v[k], m, 64);
  }
}

// f32 [rows, ncols] (ld ldsrc) -> bf16 [rows, ldp], zero-padded cols ncols..ldp
__global__ __launch_bounds__(64) void k_f2b(const float* __restrict__ src, int ncols,
    int ldsrc, unsigned short* __restrict__ dst, int ldp){
  int r = blockIdx.x, t = threadIdx.x;
  for (int c = t; c < ldp; c += 64)
    dst[(size_t)r * ldp + c] = (c < ncols) ? f2b(src[(size_t)r * ldsrc + c]) : (unsigned short)0;
}

__global__ __launch_bounds__(64) void k_rnorm(const float* __restrict__ rt,
    const float* __restrict__ arh, const float* __restrict__ are,
    float* __restrict__ ra1h, float* __restrict__ ra1e){
  int r = blockIdx.x, lane = threadIdx.x;
  bool m1 = (lane + 64 < RHd);
  float v0 = rt[r * RHd + lane];
  float v1 = m1 ? rt[r * RHd + lane + 64] : 0.f;
  float s[3];
  s[0] = v0 * v0 + v1 * v1;
  s[1] = v0 * arh[RHd + lane] + (m1 ? v1 * arh[RHd + lane + 64] : 0.f);
  s[2] = v0 * are[RHd + lane] + (m1 ? v1 * are[RHd + lane + 64] : 0.f);
  wredsumN<3>(s);
  float inv = 0.5f / fmaxf(sqrtf(s[0]), 1e-12f);
  if (!lane){
    ra1h[r] = s[1] * inv;
    ra1e[r] = s[2] * inv;
  }
}

__global__ void k_count(const int* __restrict__ dst, int* __restrict__ degi){
  int e = blockIdx.x * blockDim.x + threadIdx.x;
  if (e < EALLe) atomicAdd(&degi[dst[e]], 1);
}

__global__ void k_dis(const int* __restrict__ degi, float* __restrict__ dis){
  int n = blockIdx.x * blockDim.x + threadIdx.x;
  if (n < Nn) dis[n] = degi[n] > 0 ? rsqrtf((float)degi[n]) : 0.f;
}

__global__ __launch_bounds__(1024) void k_scan(const int* __restrict__ degi,
    int* __restrict__ ptr, int* __restrict__ cur){
  __shared__ int s[1024];
  int t = threadIdx.x;
  const int per = (Nn + 1023) / 1024;
  int b0 = t * per; if (b0 > Nn) b0 = Nn;
  int b1 = b0 + per; if (b1 > Nn) b1 = Nn;
  int sum = 0;
  for (int i = b0; i < b1; i++) sum += degi[i];
  s[t] = sum;
  __syncthreads();
  for (int off = 1; off < 1024; off <<= 1){
    int v = (t >= off) ? s[t - off] : 0;
    __syncthreads();
    s[t] += v;
    __syncthreads();
  }
  int run = (t > 0) ? s[t - 1] : 0;
  for (int i = b0; i < b1; i++){
    ptr[i] = run; cur[i] = run; run += degi[i];
  }
  if (t == 1023) ptr[Nn] = s[1023];
}

__global__ void k_scatter(const int* __restrict__ src, const int* __restrict__ dst,
    int* __restrict__ cur, int* __restrict__ csr_src){
  int e = blockIdx.x * blockDim.x + threadIdx.x;
  if (e >= EALLe) return;
  int pos = atomicAdd(&cur[dst[e]], 1);
  csr_src[pos] = src[e];
}

// GCN SpMM + relu, gathering from a bf16 table (ld ldx)
__global__ __launch_bounds__(64) void k_gcnb(const unsigned short* __restrict__ x, int ldx,
    const int* __restrict__ ptr, const int* __restrict__ src,
    const float* __restrict__ dis, float* __restrict__ out){
  int i = blockIdx.x, lane = threadIdx.x;
  int p0 = ptr[i], p1 = ptr[i + 1];
  float di = dis[i];
  float a0 = 0.f, a1 = 0.f, a2 = 0.f, a3 = 0.f, a4 = 0.f;
  for (int k = p0; k < p1; k++){
    int j = src[k];
    float w = di * dis[j];
    const unsigned short* xr = x + (size_t)j * ldx;
    a0 += w * b2f(xr[lane]);
    a1 += w * b2f(xr[lane + 64]);
    a2 += w * b2f(xr[lane + 128]);
    a3 += w * b2f(xr[lane + 192]);
    if (lane < EHd - 256) a4 += w * b2f(xr[lane + 256]);
  }
  float* orow = out + (size_t)i * EHd;
  orow[lane] = fmaxf(a0, 0.f);
  orow[lane + 64] = fmaxf(a1, 0.f);
  orow[lane + 128] = fmaxf(a2, 0.f);
  orow[lane + 192] = fmaxf(a3, 0.f);
  if (lane < EHd - 256) orow[lane + 256] = fmaxf(a4, 0.f);
}

// bf16 MFMA GEMM: out = epi( Xb[nrows,Kp]bf16 @ Wb[M,Kp]bf16^T ).
// 64x64 tile, 4 waves, mfma_f32_16x16x32_bf16. EPI 0=relu, 1=highway.
// MIR=1: also write bf16 copy of output. W K-pad rows are exact zeros, so
// garbage in X pad cols contributes 0.
template<int EPI, int MIR>
__global__ __launch_bounds__(256) void k_gemmb(
    const unsigned short* __restrict__ Xb, int ldxb, int nrows,
    const unsigned short* __restrict__ Wb, int Kp, int M,
    const float* __restrict__ bias,
    const float* __restrict__ X2, int ldx2,
    const float* __restrict__ Xf, int ldxf,
    float* __restrict__ out, int ldo,
    unsigned short* __restrict__ mir, int ldmir){
  __shared__ unsigned short Xs[64][40];
  __shared__ unsigned short Ws[64][40];
  int t = threadIdx.x;
  int wv = t >> 6, lane = t & 63;
  int c0 = blockIdx.x * 64, r0 = blockIdx.y * 64;
  int srow = t >> 2, skoff = (t & 3) * 8;
  int gxr = r0 + srow, gwr = c0 + srow;
  f32x4 acc[4] = {};
  for (int k0 = 0; k0 < Kp; k0 += 32){
    short8 xv = {0,0,0,0,0,0,0,0};
    short8 wv8 = {0,0,0,0,0,0,0,0};
    if (gxr < nrows) xv = *(const short8*)&Xb[(size_t)gxr * ldxb + k0 + skoff];
    if (gwr < M)     wv8 = *(const short8*)&Wb[(size_t)gwr * Kp + k0 + skoff];
    __syncthreads();
    *(short8*)&Xs[srow][skoff] = xv;
    *(short8*)&Ws[srow][skoff] = wv8;
    __syncthreads();
    int arow = wv * 16 + (lane & 15);
    int kk = (lane >> 4) * 8;
    short8 af = *(const short8*)&Xs[arow][kk];
#pragma unroll
    for (int j = 0; j < 4; j++){
      short8 bf = *(const short8*)&Ws[j * 16 + (lane & 15)][kk];
      acc[j] = __builtin_amdgcn_mfma_f32_16x16x32_bf16(af, bf, acc[j], 0, 0, 0);
    }
  }
  int rbase = r0 + wv * 16 + (lane >> 4) * 4;
  int cbase = c0 + (lane & 15);
#pragma unroll
  for (int j = 0; j < 4; j++){
    int c = cbase + j * 16;
    if (c >= M) continue;
#pragma unroll
    for (int r = 0; r < 4; r++){
      int row = rbase + r;
      if (row >= nrows) continue;
      float v = acc[j][r];
      float o;
      if (EPI == 0){
        o = fmaxf(v, 0.f);
      } else {
        float g = 1.f / (1.f + expf(-(v + bias[c])));
        o = g * X2[(size_t)row * ldx2 + c] + (1.f - g) * Xf[(size_t)row * ldxf + c];
      }
      out[(size_t)row * ldo + c] = o;
      if (MIR) mir[(size_t)row * ldmir + c] = f2b(o);
    }
  }
}

// per-node precompute for gat_e (xm/xo live in proj with ld 600); xn stored bf16 ld 152
__global__ __launch_bounds__(64) void k_ndots2(
    const float* __restrict__ xm, const float* __restrict__ xo, int ldp,
    const float* __restrict__ v2m, const float* __restrict__ v3m,
    const float* __restrict__ v2o, const float* __restrict__ v3o,
    const float* __restrict__ v4,
    unsigned short* __restrict__ xnb, float* __restrict__ pm,
    float* __restrict__ po, float* __restrict__ nv4){
  int n = blockIdx.x, lane = threadIdx.x;
  bool m2 = lane < (CHd - 128);
  const float* mr = xm + (size_t)n * ldp;
  const float* orw = xo + (size_t)n * ldp;
  float m0 = mr[lane], m1 = mr[lane + 64], mv2 = m2 ? mr[lane + 128] : 0.f;
  float o0 = orw[lane], o1 = orw[lane + 64], o2 = m2 ? orw[lane + 128] : 0.f;
  float s[4];
  s[0] = m0 * m0 + m1 * m1 + mv2 * mv2;
  s[1] = o0 * v2o[lane] + o1 * v2o[lane + 64] + (m2 ? o2 * v2o[lane + 128] : 0.f);
  s[2] = o0 * v3o[lane] + o1 * v3o[lane + 64] + (m2 ? o2 * v3o[lane + 128] : 0.f);
  s[3] = o0 * v4[lane]  + o1 * v4[lane + 64]  + (m2 ? o2 * v4[lane + 128]  : 0.f);
  wredsumN<4>(s);
  float inv = 1.f / fmaxf(sqrtf(s[0]), 1e-12f);
  float n0 = m0 * inv, n1 = m1 * inv, n2 = mv2 * inv;
  unsigned short* xr = xnb + (size_t)n * 152;
  xr[lane] = f2b(n0); xr[lane + 64] = f2b(n1);
  if (m2) xr[lane + 128] = f2b(n2);
  float d[2];
  d[0] = n0 * v2m[lane] + n1 * v2m[lane + 64] + (m2 ? n2 * v2m[lane + 128] : 0.f);
  d[1] = n0 * v3m[lane] + n1 * v3m[lane + 64] + (m2 ? n2 * v3m[lane + 128] : 0.f);
  wredsumN<2>(d);
  if (!lane){
    pm[n] = d[0] + 0.25f * d[1];
    po[n] = s[1] + 0.25f * s[2];
    nv4[n] = s[3];
  }
}

__global__ __launch_bounds__(256) void k_e2sum(
    const int* __restrict__ im, const int* __restrict__ io,
    const int* __restrict__ rel, const int* __restrict__ ci,
    const float* __restrict__ pm, const float* __restrict__ po,
    const float* __restrict__ ra1,
    float* __restrict__ es2, float* __restrict__ csum_p, int* __restrict__ ccnt_p){
  __shared__ float ls[Cc];
  __shared__ int lc[Cc];
  int t = threadIdx.x;
  for (int c = t; c < Cc; c += 256){ ls[c] = 0.f; lc[c] = 0; }
  __syncthreads();
  for (int e = blockIdx.x * 256 + t; e < Ee; e += gridDim.x * 256){
    float v = lrelu01(po[io[e]] + pm[im[e]] + ra1[rel[e]]);
    float s = expf(v);
    es2[e] = s;
    int c = ci[e];
    atomicAdd(&ls[c], s);
    atomicAdd(&lc[c], 1);
  }
  __syncthreads();
  for (int c = t; c < Cc; c += 256){
    if (lc[c]){
      atomicAdd(&csum_p[c * 16], ls[c]);
      atomicAdd(&ccnt_p[c * 16], lc[c]);
    }
  }
}

__global__ __launch_bounds__(256) void k_cscan(const int* __restrict__ ccnt_p,
    int* __restrict__ cstart, int* __restrict__ ccur_p){
  __shared__ int s[Cc + 1];
  int t = threadIdx.x;
  if (t == 0){
    int run = 0;
    for (int c = 0; c < Cc; c++){ s[c] = run; run += ccnt_p[c * 16]; }
    s[Cc] = run;
  }
  __syncthreads();
  if (t <= Cc) cstart[t] = s[t];
  if (t < Cc) ccur_p[t * 16] = s[t];
}

__global__ __launch_bounds__(256) void k_cscatter(
    const int* __restrict__ ci, const int* __restrict__ im,
    const float* __restrict__ es2,
    int* __restrict__ ccur_p, int* __restrict__ crows, float* __restrict__ cw){
  __shared__ int lcnt[Cc];
  __shared__ int lbase[Cc];
  int t = threadIdx.x;
  int epb = (Ee + gridDim.x - 1) / gridDim.x;
  int e0 = blockIdx.x * epb, e1 = e0 + epb; if (e1 > Ee) e1 = Ee;
  for (int c = t; c < Cc; c += 256) lcnt[c] = 0;
  __syncthreads();
  int myr[8], myc[8], mye[8]; int cnt = 0;
  for (int e = e0 + t; e < e1; e += 256){
    int c = ci[e];
    myr[cnt] = atomicAdd(&lcnt[c], 1);
    myc[cnt] = c; mye[cnt] = e; cnt++;
  }
  __syncthreads();
  for (int c = t; c < Cc; c += 256)
    lbase[c] = lcnt[c] ? atomicAdd(&ccur_p[c * 16], lcnt[c]) : 0;
  __syncthreads();
  for (int q = 0; q < cnt; q++){
    int pos = lbase[myc[q]] + myr[q];
    int e = mye[q];
    crows[pos] = im[im[e]];
    cw[pos] = es2[e];
  }
}

// one block per class; xn gathered as bf16 (ld 152)
__global__ __launch_bounds__(192) void k_xclassB(
    const int* __restrict__ cstart, const int* __restrict__ crows,
    const float* __restrict__ cw, const float* __restrict__ csum_p,
    const unsigned short* __restrict__ xnb, float* __restrict__ x_class){
  int c = blockIdx.x, t = threadIdx.x;
  int p0 = cstart[c], p1 = cstart[c + 1];
  bool act = t < CHd;
  float acc = 0.f;
  if (p1 > p0){
    float inv = 1.f / csum_p[c * 16];
    int k = p0;
    for (; k + 4 <= p1; k += 4){
      int r0 = crows[k], r1 = crows[k + 1], r2 = crows[k + 2], r3 = crows[k + 3];
      float w0 = cw[k] * inv, w1 = cw[k + 1] * inv, w2 = cw[k + 2] * inv, w3 = cw[k + 3] * inv;
      if (act){
        acc += w0 * b2f(xnb[(size_t)r0 * 152 + t]) + w1 * b2f(xnb[(size_t)r1 * 152 + t])
             + w2 * b2f(xnb[(size_t)r2 * 152 + t]) + w3 * b2f(xnb[(size_t)r3 * 152 + t]);
      }
    }
    for (; k < p1; k++){
      if (act) acc += cw[k] * inv * b2f(xnb[(size_t)crows[k] * 152 + t]);
    }
  }
  if (act) x_class[c * CHd + t] = acc;
}

__global__ __launch_bounds__(256) void k_classfinal(
    const float* __restrict__ x_class, const float* __restrict__ acv,
    const float* __restrict__ nv4, const int* __restrict__ cls_ent,
    float* __restrict__ outb){
  __shared__ float v[Cc];
  __shared__ float g[Cc];
  __shared__ int ce[Cc];
  int t = threadIdx.x;
  if (t < Cc){
    ce[t] = cls_ent[t];
    float dot = 0.f;
    for (int f = 0; f < CHd; f++) dot += x_class[t * CHd + f] * acv[f];
    v[t] = lrelu01(dot + nv4[ce[t]]);
  }
  __syncthreads();
  if (t < Cc){
    int sgm = ce[t];
    float m = -3.0e38f;
    for (int c2 = 0; c2 < Cc; c2++) if (ce[c2] == sgm) m = fmaxf(m, v[c2]);
    float sum = 0.f;
    for (int c2 = 0; c2 < Cc; c2++) if (ce[c2] == sgm) sum += expf(v[c2] - m);
    g[t] = expf(v[t] - m) / sum;
  }
  __syncthreads();
  for (int idx = t; idx < Cc * CHd; idx += 256){
    int c = idx / CHd, f = idx - c * CHd;
    atomicAdd(&outb[(size_t)ce[c] * CHd + f], g[c] * x_class[c * CHd + f]);
  }
}

// per node dot of bf16 x1b row with gat_ai / gat_aj
__global__ __launch_bounds__(64) void k_s12(const unsigned short* __restrict__ x1b,
    const float* __restrict__ ai, const float* __restrict__ aj,
    float* __restrict__ s1, float* __restrict__ s2){
  int n = blockIdx.x, lane = threadIdx.x;
  const unsigned short* xr = x1b + (size_t)n * 600;
  float sa = 0.f, sb = 0.f;
#pragma unroll
  for (int u = 0; u < 10; u++){
    int f = lane + u * 64;
    if (f < 600){
      float x = b2f(xr[f]);
      sa += x * ai[f];
      sb += x * aj[f];
    }
  }
  float s[2] = { sa, sb };
  wredsumN<2>(s);
  if (!lane){ s1[n] = s[0]; s2[n] = s[1]; }
}

// final GAT over CSR: LDS-precomputed edge weights, bf16 feature gather,
// f32 copy of x into d_out[:, :300]
__global__ __launch_bounds__(256) void k_gat(const float* __restrict__ x1,
    const unsigned short* __restrict__ x1b,
    const int* __restrict__ ptr, const int* __restrict__ src,
    const float* __restrict__ s1, const float* __restrict__ s2,
    float* __restrict__ dout){
  __shared__ float wl[128];
  __shared__ int jl[128];
  int i = blockIdx.x, t = threadIdx.x;
  float* orow = dout + (size_t)i * 900;
  const float* xi = x1 + (size_t)i * 600;
  for (int f = t; f < 300; f += 256) orow[f] = xi[f];
  int p0 = ptr[i], p1 = ptr[i + 1];
  if (p0 == p1){
    for (int f = t; f < 600; f += 256) orow[300 + f] = 0.f;
    return;
  }
  float s1i = s1[i];
  float acc0 = 0.f, acc1 = 0.f, acc2 = 0.f, den = 0.f;
  for (int base = p0; base < p1; base += 128){
    int k = base + t;
    if (t < 128 && k < p1){
      int j = src[k];
      jl[t] = j;
      wl[t] = expf(lrelu01(s1i + s2[j]));
    }
    __syncthreads();
    int lim = p1 - base; if (lim > 128) lim = 128;
    for (int q = 0; q < lim; q++){
      float w = wl[q];
      int j = jl[q];
      den += w;
      const unsigned short* xj = x1b + (size_t)j * 600;
      acc0 += w * b2f(xj[t]);
      acc1 += w * b2f(xj[t + 256]);
      if (t < 88) acc2 += w * b2f(xj[t + 512]);
    }
    __syncthreads();
  }
  float invd = 1.f / den;
  orow[300 + t] = fmaxf(acc0 * invd, 0.f);
  orow[300 + t + 256] = fmaxf(acc1 * invd, 0.f);
  if (t < 88) orow[300 + t + 512] = fmaxf(acc2 * invd, 0.f);
}

extern "C" void kernel_launch(void* const* d_in, const int* in_sizes, int n_in,
                              void* d_out, int out_size, void* d_ws, size_t ws_size,
                              hipStream_t stream) {
  const float* x_e    = (const float*)d_in[0];
  const int*   ei     = (const int*)d_in[1];
  const int*   rel    = (const int*)d_in[2];
  const int*   eall   = (const int*)d_in[3];
  const int*   cih    = (const int*)d_in[5];
  const int*   hcls   = (const int*)d_in[6];
  const int*   cit    = (const int*)d_in[7];
  const int*   tcls   = (const int*)d_in[8];
  const float* remb   = (const float*)d_in[9];
  const float* hw1w   = (const float*)d_in[10];
  const float* hw1b   = (const float*)d_in[11];
  const float* hw2w   = (const float*)d_in[12];
  const float* hw2b   = (const float*)d_in[13];
  const float* h2r_ac = (const float*)d_in[14];
  const float* h2r_ar = (const float*)d_in[15];
  const float* h2r_wh = (const float*)d_in[16];
  const float* h2r_wt = (const float*)d_in[17];
  const float* h2r_hww= (const float*)d_in[18];
  const float* h2r_hwb= (const float*)d_in[19];
  const float* et_ac  = (const float*)d_in[20];
  const float* et_ar  = (const float*)d_in[21];
  const float* et_wh  = (const float*)d_in[22];
  const float* et_wt  = (const float*)d_in[23];
  const float* et_hww = (const float*)d_in[24];
  const float* et_hwb = (const float*)d_in[25];
  const float* gai    = (const float*)d_in[26];
  const float* gaj    = (const float*)d_in[27];
  float* out = (float*)d_out;

  // ---- workspace allocator ----
  char* wsp = (char*)d_ws;
  auto alloc = [&](size_t nbytes) -> void* {
    void* p = (void*)wsp;
    wsp += (nbytes + 255) & ~(size_t)255;
    return p;
  };
  float* ra1h = (float*)alloc(Rr * 4);
  float* ra1e = (float*)alloc(Rr * 4);
  float* dis  = (float*)alloc(Nn * 4);
  int* degi    = (int*)alloc(Nn * 4);
  int* csr_ptr = (int*)alloc((Nn + 1) * 4);
  int* csr_cur = (int*)alloc(Nn * 4);
  int* csr_src = (int*)alloc((size_t)EALLe * 4);
  float* x1  = (float*)alloc((size_t)Nn * 600 * 4);
  float* es2 = (float*)alloc((size_t)Ee * 4);
  float* pm  = (float*)alloc(Nn * 4);
  float* po  = (float*)alloc(Nn * 4);
  float* nv4 = (float*)alloc(Nn * 4);
  float* csum_p = (float*)alloc(Cc * 16 * 4);
  int*   ccnt_p = (int*)alloc(Cc * 16 * 4);
  int*   ccur_p = (int*)alloc(Cc * 16 * 4);
  int*   cstart = (int*)alloc((Cc + 1) * 4);
  int*   crows  = (int*)alloc((size_t)Ee * 4);
  float* cw     = (float*)alloc((size_t)Ee * 4);
  float* x_class = (float*)alloc(Cc * CHd * 4);
  float* s1v = (float*)alloc(Nn * 4);
  float* s2v = (float*)alloc(Nn * 4);
  // bf16 arenas
  unsigned short* arenaA = (unsigned short*)alloc((size_t)Nn * 320 * 2);
  unsigned short* arenaB = (unsigned short*)alloc((size_t)Nn * 320 * 2);
  unsigned short* x1b    = (unsigned short*)alloc(((size_t)Nn * 600 + 64) * 2);
  unsigned short* xnb    = (unsigned short*)alloc((size_t)Nn * 152 * 2);
  unsigned short* xob    = (unsigned short*)alloc((size_t)Nn * 160 * 2);
  unsigned short* w1b    = (unsigned short*)alloc((size_t)300 * 320 * 2);
  unsigned short* w2b    = (unsigned short*)alloc((size_t)300 * 320 * 2);
  unsigned short* wcatb  = (unsigned short*)alloc((size_t)600 * 320 * 2);
  unsigned short* hwwbA  = (unsigned short*)alloc((size_t)150 * 160 * 2);
  unsigned short* hwwbB  = (unsigned short*)alloc((size_t)150 * 160 * 2);

  // d_out staging layout (all dead before k_gat rewrites d_out)
  float* h1   = out;
  float* gbuf = out + (size_t)Nn * EHd;
  float* proj = out;
  float* outb = out + (size_t)Nn * 600;

  // ---- prologue: r_emb norm, degrees, CSR, weight conversions ----
  hipMemsetAsync(degi, 0, Nn * 4, stream);
  k_rnorm<<<Rr, 64, 0, stream>>>(remb, h2r_ar, et_ar, ra1h, ra1e);
  k_count<<<cdiv_h(EALLe, 256), 256, 0, stream>>>(eall + EALLe, degi);
  k_dis<<<cdiv_h(Nn, 256), 256, 0, stream>>>(degi, dis);
  k_scan<<<1, 1024, 0, stream>>>(degi, csr_ptr, csr_cur);
  k_scatter<<<cdiv_h(EALLe, 256), 256, 0, stream>>>(eall, eall + EALLe, csr_cur, csr_src);
  k_f2b<<<300, 64, 0, stream>>>(hw1w, 300, 300, w1b, 320);
  k_f2b<<<300, 64, 0, stream>>>(hw2w, 300, 300, w2b, 320);
  k_f2b<<<150, 64, 0, stream>>>(h2r_wh, 300, 300, wcatb + (size_t)0   * 320, 320);
  k_f2b<<<150, 64, 0, stream>>>(h2r_wt, 300, 300, wcatb + (size_t)150 * 320, 320);
  k_f2b<<<150, 64, 0, stream>>>(et_wh,  300, 300, wcatb + (size_t)300 * 320, 320);
  k_f2b<<<150, 64, 0, stream>>>(et_wt,  300, 300, wcatb + (size_t)450 * 320, 320);
  k_f2b<<<150, 64, 0, stream>>>(h2r_hww, 150, 150, hwwbA, 160);
  k_f2b<<<150, 64, 0, stream>>>(et_hww,  150, 150, hwwbB, 160);
  k_f2b<<<Nn, 64, 0, stream>>>(x_e, 300, 300, arenaA, 320);

  // ---- GCN + highway x2 (bf16 gathers, bf16 MFMA GEMMs, mirror-chained) ----
  k_gcnb<<<Nn, 64, 0, stream>>>(arenaA, 320, csr_ptr, csr_src, dis, gbuf);
  k_gemmb<1,1><<<dim3(5, cdiv_h(Nn, 64)), 256, 0, stream>>>(
      arenaA, 320, Nn, w1b, 320, 300, hw1b, gbuf, 300, x_e, 300, h1, 300, arenaB, 320);
  k_gcnb<<<Nn, 64, 0, stream>>>(arenaB, 320, csr_ptr, csr_src, dis, gbuf);
  // x1 cols 0..299 (f32) + bf16 mirror into x1b cols 0..299
  k_gemmb<1,1><<<dim3(5, cdiv_h(Nn, 64)), 256, 0, stream>>>(
      arenaB, 320, Nn, w2b, 320, 300, hw2b, gbuf, 300, h1, 300, x1, 600, x1b, 600);

  // ---- batched projections: [xh_A | xt_A | xh_B | xt_B] = relu(x @ wcat^T) ----
  // reads x1b cols 0..319 (pad cols annihilated by zero W rows)
  k_gemmb<0,0><<<dim3(10, cdiv_h(Nn, 64)), 256, 0, stream>>>(
      x1b, 600, Nn, wcatb, 320, 600, nullptr, nullptr, 0, nullptr, 0, proj, 600,
      nullptr, 0);

  // ---- gat_e (two calls) ----
  struct GP {
    const float* xm; const float* xo;
    const int* im; const int* io;
    const int* ci; const int* cls_ent;
    const float* ra1;
    const float* v2m; const float* v2o;
    const float* v3m; const float* v3o;
    const float* v4;  const float* acv;
    const unsigned short* hwwb; const float* hwb;
    float* x1out; unsigned short* x1outb;
  };
  const int* eh = ei;
  const int* et = ei + Ee;
  GP A = { proj + 150, proj + 0, et, eh, cih, hcls, ra1h,
           h2r_ac + 5 * CHd, h2r_ac + 1 * CHd,
           h2r_ac + 6 * CHd, h2r_ac + 2 * CHd,
           h2r_ac + 3 * CHd, h2r_ac + 7 * CHd,
           hwwbA, h2r_hwb, x1 + 300, x1b + 300 };
  GP B = { proj + 300, proj + 450, eh, et, cit, tcls, ra1e,
           et_ac + 1 * CHd, et_ac + 5 * CHd,
           et_ac + 2 * CHd, et_ac + 6 * CHd,
           et_ac + 3 * CHd, et_ac + 7 * CHd,
           hwwbB, et_hwb, x1 + 450, x1b + 450 };

  GP calls[2] = { A, B };
  for (int ci_ = 0; ci_ < 2; ci_++){
    const GP& P = calls[ci_];
    hipMemsetAsync(csum_p, 0, Cc * 16 * 4, stream);
    hipMemsetAsync(ccnt_p, 0, Cc * 16 * 4, stream);
    hipMemsetAsync(outb, 0, (size_t)Nn * CHd * 4, stream);
    k_ndots2<<<Nn, 64, 0, stream>>>(P.xm, P.xo, 600, P.v2m, P.v3m, P.v2o, P.v3o, P.v4,
                                    xnb, pm, po, nv4);
    k_e2sum<<<CB, 256, 0, stream>>>(P.im, P.io, rel, P.ci, pm, po, P.ra1,
                                    es2, csum_p, ccnt_p);
    k_cscan<<<1, 256, 0, stream>>>(ccnt_p, cstart, ccur_p);
    k_cscatter<<<CB, 256, 0, stream>>>(P.ci, P.im, es2, ccur_p, crows, cw);
    k_xclassB<<<Cc, 192, 0, stream>>>(cstart, crows, cw, csum_p, xnb, x_class);
    k_classfinal<<<1, 256, 0, stream>>>(x_class, P.acv, nv4, P.cls_ent, outb);
    // highway(xo, outb) via bf16 GEMM; mirror into x1b slice
    k_f2b<<<Nn, 64, 0, stream>>>(P.xo, 150, 600, xob, 160);
    k_gemmb<1,1><<<dim3(3, cdiv_h(Nn, 64)), 256, 0, stream>>>(
        xob, 160, Nn, P.hwwb, 160, 150, P.hwb, outb, 150, P.xo, 600, P.x1out, 600,
        P.x1outb, 600);
  }

  // ---- final GAT over x1 ----
  k_s12<<<Nn, 64, 0, stream>>>(x1b, gai, gaj, s1v, s2v);
  k_gat<<<Nn, 256, 0, stream>>>(x1, x1b, csr_ptr, csr_src, s1v, s2v, out);
}

// Round 8
// 648.397 us; speedup vs baseline: 3.1614x; 1.2383x over previous
//
#include <hip/hip_runtime.h>
#include <math.h>

#define Nn 20000
#define Ee 120000
#define EALLe 240000
#define Cc 150
#define Rr 1000
#define EHd 300
#define RHd 100
#define CHd 150
#define CB 128   // blocks for edge-pass kernels (per-thread ranks fit in 4)
#define XSPL 16  // splits per class for x_class accumulation

static inline int cdiv_h(int a, int b){ return (a + b - 1) / b; }

typedef __attribute__((ext_vector_type(8))) short short8;
typedef __attribute__((ext_vector_type(4))) float f32x4;

__device__ __forceinline__ float lrelu01(float x){ return x > 0.f ? x : 0.01f * x; }

__device__ __forceinline__ unsigned short f2b(float f){
  unsigned int u = __float_as_uint(f);
  unsigned int r = (u + 0x7FFFu + ((u >> 16) & 1u)) >> 16;
  return (unsigned short)r;
}
__device__ __forceinline__ float b2f(unsigned short u){
  return __uint_as_float(((unsigned int)u) << 16);
}

template<int Kq>
__device__ __forceinline__ void wredsumN(float* v){
#pragma unroll
  for (int m = 32; m >= 1; m >>= 1){
#pragma unroll
    for (int k = 0; k < Kq; k++) v[k] += __shfl_xor(v[k], m, 64);
  }
}

// f32 [rows, ncols] (ld ldsrc) -> bf16 [rows, ldp], zero-padded cols ncols..ldp
__global__ __launch_bounds__(64) void k_f2b(const float* __restrict__ src, int ncols,
    int ldsrc, unsigned short* __restrict__ dst, int ldp){
  int r = blockIdx.x, t = threadIdx.x;
  for (int c = t; c < ldp; c += 64)
    dst[(size_t)r * ldp + c] = (c < ncols) ? f2b(src[(size_t)r * ldsrc + c]) : (unsigned short)0;
}

__global__ __launch_bounds__(64) void k_rnorm(const float* __restrict__ rt,
    const float* __restrict__ arh, const float* __restrict__ are,
    float* __restrict__ ra1h, float* __restrict__ ra1e){
  int r = blockIdx.x, lane = threadIdx.x;
  bool m1 = (lane + 64 < RHd);
  float v0 = rt[r * RHd + lane];
  float v1 = m1 ? rt[r * RHd + lane + 64] : 0.f;
  float s[3];
  s[0] = v0 * v0 + v1 * v1;
  s[1] = v0 * arh[RHd + lane] + (m1 ? v1 * arh[RHd + lane + 64] : 0.f);
  s[2] = v0 * are[RHd + lane] + (m1 ? v1 * are[RHd + lane + 64] : 0.f);
  wredsumN<3>(s);
  float inv = 0.5f / fmaxf(sqrtf(s[0]), 1e-12f);
  if (!lane){
    ra1h[r] = s[1] * inv;
    ra1e[r] = s[2] * inv;
  }
}

__global__ void k_count(const int* __restrict__ dst, int* __restrict__ degi){
  int e = blockIdx.x * blockDim.x + threadIdx.x;
  if (e < EALLe) atomicAdd(&degi[dst[e]], 1);
}

__global__ void k_dis(const int* __restrict__ degi, float* __restrict__ dis){
  int n = blockIdx.x * blockDim.x + threadIdx.x;
  if (n < Nn) dis[n] = degi[n] > 0 ? rsqrtf((float)degi[n]) : 0.f;
}

__global__ __launch_bounds__(1024) void k_scan(const int* __restrict__ degi,
    int* __restrict__ ptr, int* __restrict__ cur){
  __shared__ int s[1024];
  int t = threadIdx.x;
  const int per = (Nn + 1023) / 1024;
  int b0 = t * per; if (b0 > Nn) b0 = Nn;
  int b1 = b0 + per; if (b1 > Nn) b1 = Nn;
  int sum = 0;
  for (int i = b0; i < b1; i++) sum += degi[i];
  s[t] = sum;
  __syncthreads();
  for (int off = 1; off < 1024; off <<= 1){
    int v = (t >= off) ? s[t - off] : 0;
    __syncthreads();
    s[t] += v;
    __syncthreads();
  }
  int run = (t > 0) ? s[t - 1] : 0;
  for (int i = b0; i < b1; i++){
    ptr[i] = run; cur[i] = run; run += degi[i];
  }
  if (t == 1023) ptr[Nn] = s[1023];
}

__global__ void k_scatter(const int* __restrict__ src, const int* __restrict__ dst,
    int* __restrict__ cur, int* __restrict__ csr_src){
  int e = blockIdx.x * blockDim.x + threadIdx.x;
  if (e >= EALLe) return;
  int pos = atomicAdd(&cur[dst[e]], 1);
  csr_src[pos] = src[e];
}

// GCN SpMM + relu, gathering from a bf16 table (ld ldx)
__global__ __launch_bounds__(64) void k_gcnb(const unsigned short* __restrict__ x, int ldx,
    const int* __restrict__ ptr, const int* __restrict__ src,
    const float* __restrict__ dis, float* __restrict__ out){
  int i = blockIdx.x, lane = threadIdx.x;
  int p0 = ptr[i], p1 = ptr[i + 1];
  float di = dis[i];
  float a0 = 0.f, a1 = 0.f, a2 = 0.f, a3 = 0.f, a4 = 0.f;
  for (int k = p0; k < p1; k++){
    int j = src[k];
    float w = di * dis[j];
    const unsigned short* xr = x + (size_t)j * ldx;
    a0 += w * b2f(xr[lane]);
    a1 += w * b2f(xr[lane + 64]);
    a2 += w * b2f(xr[lane + 128]);
    a3 += w * b2f(xr[lane + 192]);
    if (lane < EHd - 256) a4 += w * b2f(xr[lane + 256]);
  }
  float* orow = out + (size_t)i * EHd;
  orow[lane] = fmaxf(a0, 0.f);
  orow[lane + 64] = fmaxf(a1, 0.f);
  orow[lane + 128] = fmaxf(a2, 0.f);
  orow[lane + 192] = fmaxf(a3, 0.f);
  if (lane < EHd - 256) orow[lane + 256] = fmaxf(a4, 0.f);
}

// bf16 MFMA GEMM: out = epi( Xb[nrows,Kp]bf16 @ Wb[M,Kp]bf16^T ).
template<int EPI, int MIR>
__global__ __launch_bounds__(256) void k_gemmb(
    const unsigned short* __restrict__ Xb, int ldxb, int nrows,
    const unsigned short* __restrict__ Wb, int Kp, int M,
    const float* __restrict__ bias,
    const float* __restrict__ X2, int ldx2,
    const float* __restrict__ Xf, int ldxf,
    float* __restrict__ out, int ldo,
    unsigned short* __restrict__ mir, int ldmir){
  __shared__ unsigned short Xs[64][40];
  __shared__ unsigned short Ws[64][40];
  int t = threadIdx.x;
  int wv = t >> 6, lane = t & 63;
  int c0 = blockIdx.x * 64, r0 = blockIdx.y * 64;
  int srow = t >> 2, skoff = (t & 3) * 8;
  int gxr = r0 + srow, gwr = c0 + srow;
  f32x4 acc[4] = {};
  for (int k0 = 0; k0 < Kp; k0 += 32){
    short8 xv = {0,0,0,0,0,0,0,0};
    short8 wv8 = {0,0,0,0,0,0,0,0};
    if (gxr < nrows) xv = *(const short8*)&Xb[(size_t)gxr * ldxb + k0 + skoff];
    if (gwr < M)     wv8 = *(const short8*)&Wb[(size_t)gwr * Kp + k0 + skoff];
    __syncthreads();
    *(short8*)&Xs[srow][skoff] = xv;
    *(short8*)&Ws[srow][skoff] = wv8;
    __syncthreads();
    int arow = wv * 16 + (lane & 15);
    int kk = (lane >> 4) * 8;
    short8 af = *(const short8*)&Xs[arow][kk];
#pragma unroll
    for (int j = 0; j < 4; j++){
      short8 bf = *(const short8*)&Ws[j * 16 + (lane & 15)][kk];
      acc[j] = __builtin_amdgcn_mfma_f32_16x16x32_bf16(af, bf, acc[j], 0, 0, 0);
    }
  }
  int rbase = r0 + wv * 16 + (lane >> 4) * 4;
  int cbase = c0 + (lane & 15);
#pragma unroll
  for (int j = 0; j < 4; j++){
    int c = cbase + j * 16;
    if (c >= M) continue;
#pragma unroll
    for (int r = 0; r < 4; r++){
      int row = rbase + r;
      if (row >= nrows) continue;
      float v = acc[j][r];
      float o;
      if (EPI == 0){
        o = fmaxf(v, 0.f);
      } else {
        float g = 1.f / (1.f + expf(-(v + bias[c])));
        o = g * X2[(size_t)row * ldx2 + c] + (1.f - g) * Xf[(size_t)row * ldxf + c];
      }
      out[(size_t)row * ldo + c] = o;
      if (MIR) mir[(size_t)row * ldmir + c] = f2b(o);
    }
  }
}

// per-node precompute for gat_e (xm/xo live in proj with ld 600); xn stored bf16 ld 152
__global__ __launch_bounds__(64) void k_ndots2(
    const float* __restrict__ xm, const float* __restrict__ xo, int ldp,
    const float* __restrict__ v2m, const float* __restrict__ v3m,
    const float* __restrict__ v2o, const float* __restrict__ v3o,
    const float* __restrict__ v4,
    unsigned short* __restrict__ xnb, float* __restrict__ pm,
    float* __restrict__ po, float* __restrict__ nv4){
  int n = blockIdx.x, lane = threadIdx.x;
  bool m2 = lane < (CHd - 128);
  const float* mr = xm + (size_t)n * ldp;
  const float* orw = xo + (size_t)n * ldp;
  float m0 = mr[lane], m1 = mr[lane + 64], mv2 = m2 ? mr[lane + 128] : 0.f;
  float o0 = orw[lane], o1 = orw[lane + 64], o2 = m2 ? orw[lane + 128] : 0.f;
  float s[4];
  s[0] = m0 * m0 + m1 * m1 + mv2 * mv2;
  s[1] = o0 * v2o[lane] + o1 * v2o[lane + 64] + (m2 ? o2 * v2o[lane + 128] : 0.f);
  s[2] = o0 * v3o[lane] + o1 * v3o[lane + 64] + (m2 ? o2 * v3o[lane + 128] : 0.f);
  s[3] = o0 * v4[lane]  + o1 * v4[lane + 64]  + (m2 ? o2 * v4[lane + 128]  : 0.f);
  wredsumN<4>(s);
  float inv = 1.f / fmaxf(sqrtf(s[0]), 1e-12f);
  float n0 = m0 * inv, n1 = m1 * inv, n2 = mv2 * inv;
  unsigned short* xr = xnb + (size_t)n * 152;
  xr[lane] = f2b(n0); xr[lane + 64] = f2b(n1);
  if (m2) xr[lane + 128] = f2b(n2);
  float d[2];
  d[0] = n0 * v2m[lane] + n1 * v2m[lane + 64] + (m2 ? n2 * v2m[lane + 128] : 0.f);
  d[1] = n0 * v3m[lane] + n1 * v3m[lane + 64] + (m2 ? n2 * v3m[lane + 128] : 0.f);
  wredsumN<2>(d);
  if (!lane){
    pm[n] = d[0] + 0.25f * d[1];
    po[n] = s[1] + 0.25f * s[2];
    nv4[n] = s[3];
  }
}

__global__ __launch_bounds__(256) void k_e2sum(
    const int* __restrict__ im, const int* __restrict__ io,
    const int* __restrict__ rel, const int* __restrict__ ci,
    const float* __restrict__ pm, const float* __restrict__ po,
    const float* __restrict__ ra1,
    float* __restrict__ es2, float* __restrict__ csum_p, int* __restrict__ ccnt_p){
  __shared__ float ls[Cc];
  __shared__ int lc[Cc];
  int t = threadIdx.x;
  for (int c = t; c < Cc; c += 256){ ls[c] = 0.f; lc[c] = 0; }
  __syncthreads();
  for (int e = blockIdx.x * 256 + t; e < Ee; e += gridDim.x * 256){
    float v = lrelu01(po[io[e]] + pm[im[e]] + ra1[rel[e]]);
    float s = expf(v);
    es2[e] = s;
    int c = ci[e];
    atomicAdd(&ls[c], s);
    atomicAdd(&lc[c], 1);
  }
  __syncthreads();
  for (int c = t; c < Cc; c += 256){
    if (lc[c]){
      atomicAdd(&csum_p[c * 16], ls[c]);
      atomicAdd(&ccnt_p[c * 16], lc[c]);
    }
  }
}

__global__ __launch_bounds__(256) void k_cscan(const int* __restrict__ ccnt_p,
    int* __restrict__ cstart, int* __restrict__ ccur_p){
  __shared__ int s[Cc + 1];
  int t = threadIdx.x;
  if (t == 0){
    int run = 0;
    for (int c = 0; c < Cc; c++){ s[c] = run; run += ccnt_p[c * 16]; }
    s[Cc] = run;
  }
  __syncthreads();
  if (t <= Cc) cstart[t] = s[t];
  if (t < Cc) ccur_p[t * 16] = s[t];
}

__global__ __launch_bounds__(256) void k_cscatter(
    const int* __restrict__ ci, const int* __restrict__ im,
    const float* __restrict__ es2,
    int* __restrict__ ccur_p, int* __restrict__ crows, float* __restrict__ cw){
  __shared__ int lcnt[Cc];
  __shared__ int lbase[Cc];
  int t = threadIdx.x;
  int epb = (Ee + gridDim.x - 1) / gridDim.x;
  int e0 = blockIdx.x * epb, e1 = e0 + epb; if (e1 > Ee) e1 = Ee;
  for (int c = t; c < Cc; c += 256) lcnt[c] = 0;
  __syncthreads();
  int myr[4], myc[4], mye[4]; int cnt = 0;
  for (int e = e0 + t; e < e1; e += 256){
    int c = ci[e];
    myr[cnt] = atomicAdd(&lcnt[c], 1);
    myc[cnt] = c; mye[cnt] = e; cnt++;
  }
  __syncthreads();
  for (int c = t; c < Cc; c += 256)
    lbase[c] = lcnt[c] ? atomicAdd(&ccur_p[c * 16], lcnt[c]) : 0;
  __syncthreads();
  for (int q = 0; q < cnt; q++){
    int pos = lbase[myc[q]] + myr[q];
    int e = mye[q];
    crows[pos] = im[im[e]];
    cw[pos] = es2[e];
  }
}

// class x_class accumulation: XSPL blocks per class, register accumulate + one
// atomicAdd per feature per block (22.5K addresses, ~16 RMW each)
__global__ __launch_bounds__(192) void k_xclassB(
    const int* __restrict__ cstart, const int* __restrict__ crows,
    const float* __restrict__ cw, const float* __restrict__ csum_p,
    const unsigned short* __restrict__ xnb, float* __restrict__ x_class){
  int c = blockIdx.x / XSPL, sp = blockIdx.x % XSPL;
  int t = threadIdx.x;
  int p0 = cstart[c], p1 = cstart[c + 1];
  int len = p1 - p0;
  if (len <= 0) return;
  int chunk = (len + XSPL - 1) / XSPL;
  int q0 = p0 + sp * chunk;
  int q1 = q0 + chunk; if (q1 > p1) q1 = p1;
  if (q0 >= q1) return;
  bool act = t < CHd;
  float inv = 1.f / csum_p[c * 16];
  float acc = 0.f;
  int k = q0;
  for (; k + 4 <= q1; k += 4){
    int r0 = crows[k], r1 = crows[k + 1], r2 = crows[k + 2], r3 = crows[k + 3];
    float w0 = cw[k] * inv, w1 = cw[k + 1] * inv, w2 = cw[k + 2] * inv, w3 = cw[k + 3] * inv;
    if (act){
      acc += w0 * b2f(xnb[(size_t)r0 * 152 + t]) + w1 * b2f(xnb[(size_t)r1 * 152 + t])
           + w2 * b2f(xnb[(size_t)r2 * 152 + t]) + w3 * b2f(xnb[(size_t)r3 * 152 + t]);
    }
  }
  for (; k < q1; k++){
    if (act) acc += cw[k] * inv * b2f(xnb[(size_t)crows[k] * 152 + t]);
  }
  if (act) atomicAdd(&x_class[c * CHd + t], acc);
}

__global__ __launch_bounds__(256) void k_classfinal(
    const float* __restrict__ x_class, const float* __restrict__ acv,
    const float* __restrict__ nv4, const int* __restrict__ cls_ent,
    float* __restrict__ outb){
  __shared__ float v[Cc];
  __shared__ float g[Cc];
  __shared__ int ce[Cc];
  int t = threadIdx.x;
  if (t < Cc){
    ce[t] = cls_ent[t];
    float dot = 0.f;
    for (int f = 0; f < CHd; f++) dot += x_class[t * CHd + f] * acv[f];
    v[t] = lrelu01(dot + nv4[ce[t]]);
  }
  __syncthreads();
  if (t < Cc){
    int sgm = ce[t];
    float m = -3.0e38f;
    for (int c2 = 0; c2 < Cc; c2++) if (ce[c2] == sgm) m = fmaxf(m, v[c2]);
    float sum = 0.f;
    for (int c2 = 0; c2 < Cc; c2++) if (ce[c2] == sgm) sum += expf(v[c2] - m);
    g[t] = expf(v[t] - m) / sum;
  }
  __syncthreads();
  for (int idx = t; idx < Cc * CHd; idx += 256){
    int c = idx / CHd, f = idx - c * CHd;
    atomicAdd(&outb[(size_t)ce[c] * CHd + f], g[c] * x_class[c * CHd + f]);
  }
}

__global__ __launch_bounds__(64) void k_s12(const unsigned short* __restrict__ x1b,
    const float* __restrict__ ai, const float* __restrict__ aj,
    float* __restrict__ s1, float* __restrict__ s2){
  int n = blockIdx.x, lane = threadIdx.x;
  const unsigned short* xr = x1b + (size_t)n * 600;
  float sa = 0.f, sb = 0.f;
#pragma unroll
  for (int u = 0; u < 10; u++){
    int f = lane + u * 64;
    if (f < 600){
      float x = b2f(xr[f]);
      sa += x * ai[f];
      sb += x * aj[f];
    }
  }
  float s[2] = { sa, sb };
  wredsumN<2>(s);
  if (!lane){ s1[n] = s[0]; s2[n] = s[1]; }
}

// final GAT over CSR: LDS-precomputed edge weights, bf16 feature gather
__global__ __launch_bounds__(256) void k_gat(const float* __restrict__ x1,
    const unsigned short* __restrict__ x1b,
    const int* __restrict__ ptr, const int* __restrict__ src,
    const float* __restrict__ s1, const float* __restrict__ s2,
    float* __restrict__ dout){
  __shared__ float wl[128];
  __shared__ int jl[128];
  int i = blockIdx.x, t = threadIdx.x;
  float* orow = dout + (size_t)i * 900;
  const float* xi = x1 + (size_t)i * 600;
  for (int f = t; f < 300; f += 256) orow[f] = xi[f];
  int p0 = ptr[i], p1 = ptr[i + 1];
  if (p0 == p1){
    for (int f = t; f < 600; f += 256) orow[300 + f] = 0.f;
    return;
  }
  float s1i = s1[i];
  float acc0 = 0.f, acc1 = 0.f, acc2 = 0.f, den = 0.f;
  for (int base = p0; base < p1; base += 128){
    int k = base + t;
    if (t < 128 && k < p1){
      int j = src[k];
      jl[t] = j;
      wl[t] = expf(lrelu01(s1i + s2[j]));
    }
    __syncthreads();
    int lim = p1 - base; if (lim > 128) lim = 128;
    for (int q = 0; q < lim; q++){
      float w = wl[q];
      int j = jl[q];
      den += w;
      const unsigned short* xj = x1b + (size_t)j * 600;
      acc0 += w * b2f(xj[t]);
      acc1 += w * b2f(xj[t + 256]);
      if (t < 88) acc2 += w * b2f(xj[t + 512]);
    }
    __syncthreads();
  }
  float invd = 1.f / den;
  orow[300 + t] = fmaxf(acc0 * invd, 0.f);
  orow[300 + t + 256] = fmaxf(acc1 * invd, 0.f);
  if (t < 88) orow[300 + t + 512] = fmaxf(acc2 * invd, 0.f);
}

extern "C" void kernel_launch(void* const* d_in, const int* in_sizes, int n_in,
                              void* d_out, int out_size, void* d_ws, size_t ws_size,
                              hipStream_t stream) {
  const float* x_e    = (const float*)d_in[0];
  const int*   ei     = (const int*)d_in[1];
  const int*   rel    = (const int*)d_in[2];
  const int*   eall   = (const int*)d_in[3];
  const int*   cih    = (const int*)d_in[5];
  const int*   hcls   = (const int*)d_in[6];
  const int*   cit    = (const int*)d_in[7];
  const int*   tcls   = (const int*)d_in[8];
  const float* remb   = (const float*)d_in[9];
  const float* hw1w   = (const float*)d_in[10];
  const float* hw1b   = (const float*)d_in[11];
  const float* hw2w   = (const float*)d_in[12];
  const float* hw2b   = (const float*)d_in[13];
  const float* h2r_ac = (const float*)d_in[14];
  const float* h2r_ar = (const float*)d_in[15];
  const float* h2r_wh = (const float*)d_in[16];
  const float* h2r_wt = (const float*)d_in[17];
  const float* h2r_hww= (const float*)d_in[18];
  const float* h2r_hwb= (const float*)d_in[19];
  const float* et_ac  = (const float*)d_in[20];
  const float* et_ar  = (const float*)d_in[21];
  const float* et_wh  = (const float*)d_in[22];
  const float* et_wt  = (const float*)d_in[23];
  const float* et_hww = (const float*)d_in[24];
  const float* et_hwb = (const float*)d_in[25];
  const float* gai    = (const float*)d_in[26];
  const float* gaj    = (const float*)d_in[27];
  float* out = (float*)d_out;

  // ---- workspace allocator ----
  char* wsp = (char*)d_ws;
  auto alloc = [&](size_t nbytes) -> void* {
    void* p = (void*)wsp;
    wsp += (nbytes + 255) & ~(size_t)255;
    return p;
  };
  float* ra1h = (float*)alloc(Rr * 4);
  float* ra1e = (float*)alloc(Rr * 4);
  float* dis  = (float*)alloc(Nn * 4);
  int* degi    = (int*)alloc(Nn * 4);
  int* csr_ptr = (int*)alloc((Nn + 1) * 4);
  int* csr_cur = (int*)alloc(Nn * 4);
  int* csr_src = (int*)alloc((size_t)EALLe * 4);
  float* x1  = (float*)alloc((size_t)Nn * 600 * 4);
  float* es2 = (float*)alloc((size_t)Ee * 4);
  float* pm  = (float*)alloc(Nn * 4);
  float* po  = (float*)alloc(Nn * 4);
  float* nv4 = (float*)alloc(Nn * 4);
  float* csum_p = (float*)alloc(Cc * 16 * 4);
  int*   ccnt_p = (int*)alloc(Cc * 16 * 4);
  int*   ccur_p = (int*)alloc(Cc * 16 * 4);
  int*   cstart = (int*)alloc((Cc + 1) * 4);
  int*   crows  = (int*)alloc((size_t)Ee * 4);
  float* cw     = (float*)alloc((size_t)Ee * 4);
  float* x_class = (float*)alloc(Cc * CHd * 4);
  float* s1v = (float*)alloc(Nn * 4);
  float* s2v = (float*)alloc(Nn * 4);
  // bf16 arenas
  unsigned short* arenaA = (unsigned short*)alloc((size_t)Nn * 320 * 2);
  unsigned short* arenaB = (unsigned short*)alloc((size_t)Nn * 320 * 2);
  unsigned short* x1b    = (unsigned short*)alloc(((size_t)Nn * 600 + 64) * 2);
  unsigned short* xnb    = (unsigned short*)alloc((size_t)Nn * 152 * 2);
  unsigned short* xob    = (unsigned short*)alloc((size_t)Nn * 160 * 2);
  unsigned short* w1b    = (unsigned short*)alloc((size_t)300 * 320 * 2);
  unsigned short* w2b    = (unsigned short*)alloc((size_t)300 * 320 * 2);
  unsigned short* wcatb  = (unsigned short*)alloc((size_t)600 * 320 * 2);
  unsigned short* hwwbA  = (unsigned short*)alloc((size_t)150 * 160 * 2);
  unsigned short* hwwbB  = (unsigned short*)alloc((size_t)150 * 160 * 2);

  // d_out staging layout (all dead before k_gat rewrites d_out)
  float* h1   = out;
  float* gbuf = out + (size_t)Nn * EHd;
  float* proj = out;
  float* outb = out + (size_t)Nn * 600;

  // ---- prologue: r_emb norm, degrees, CSR, weight conversions ----
  hipMemsetAsync(degi, 0, Nn * 4, stream);
  k_rnorm<<<Rr, 64, 0, stream>>>(remb, h2r_ar, et_ar, ra1h, ra1e);
  k_count<<<cdiv_h(EALLe, 256), 256, 0, stream>>>(eall + EALLe, degi);
  k_dis<<<cdiv_h(Nn, 256), 256, 0, stream>>>(degi, dis);
  k_scan<<<1, 1024, 0, stream>>>(degi, csr_ptr, csr_cur);
  k_scatter<<<cdiv_h(EALLe, 256), 256, 0, stream>>>(eall, eall + EALLe, csr_cur, csr_src);
  k_f2b<<<300, 64, 0, stream>>>(hw1w, 300, 300, w1b, 320);
  k_f2b<<<300, 64, 0, stream>>>(hw2w, 300, 300, w2b, 320);
  k_f2b<<<150, 64, 0, stream>>>(h2r_wh, 300, 300, wcatb + (size_t)0   * 320, 320);
  k_f2b<<<150, 64, 0, stream>>>(h2r_wt, 300, 300, wcatb + (size_t)150 * 320, 320);
  k_f2b<<<150, 64, 0, stream>>>(et_wh,  300, 300, wcatb + (size_t)300 * 320, 320);
  k_f2b<<<150, 64, 0, stream>>>(et_wt,  300, 300, wcatb + (size_t)450 * 320, 320);
  k_f2b<<<150, 64, 0, stream>>>(h2r_hww, 150, 150, hwwbA, 160);
  k_f2b<<<150, 64, 0, stream>>>(et_hww,  150, 150, hwwbB, 160);
  k_f2b<<<Nn, 64, 0, stream>>>(x_e, 300, 300, arenaA, 320);

  // ---- GCN + highway x2 (bf16 gathers, bf16 MFMA GEMMs, mirror-chained) ----
  k_gcnb<<<Nn, 64, 0, stream>>>(arenaA, 320, csr_ptr, csr_src, dis, gbuf);
  k_gemmb<1,1><<<dim3(5, cdiv_h(Nn, 64)), 256, 0, stream>>>(
      arenaA, 320, Nn, w1b, 320, 300, hw1b, gbuf, 300, x_e, 300, h1, 300, arenaB, 320);
  k_gcnb<<<Nn, 64, 0, stream>>>(arenaB, 320, csr_ptr, csr_src, dis, gbuf);
  k_gemmb<1,1><<<dim3(5, cdiv_h(Nn, 64)), 256, 0, stream>>>(
      arenaB, 320, Nn, w2b, 320, 300, hw2b, gbuf, 300, h1, 300, x1, 600, x1b, 600);

  // ---- batched projections: [xh_A | xt_A | xh_B | xt_B] = relu(x @ wcat^T) ----
  k_gemmb<0,0><<<dim3(10, cdiv_h(Nn, 64)), 256, 0, stream>>>(
      x1b, 600, Nn, wcatb, 320, 600, nullptr, nullptr, 0, nullptr, 0, proj, 600,
      nullptr, 0);

  // ---- gat_e (two calls) ----
  struct GP {
    const float* xm; const float* xo;
    const int* im; const int* io;
    const int* ci; const int* cls_ent;
    const float* ra1;
    const float* v2m; const float* v2o;
    const float* v3m; const float* v3o;
    const float* v4;  const float* acv;
    const unsigned short* hwwb; const float* hwb;
    float* x1out; unsigned short* x1outb;
  };
  const int* eh = ei;
  const int* et = ei + Ee;
  GP A = { proj + 150, proj + 0, et, eh, cih, hcls, ra1h,
           h2r_ac + 5 * CHd, h2r_ac + 1 * CHd,
           h2r_ac + 6 * CHd, h2r_ac + 2 * CHd,
           h2r_ac + 3 * CHd, h2r_ac + 7 * CHd,
           hwwbA, h2r_hwb, x1 + 300, x1b + 300 };
  GP B = { proj + 300, proj + 450, eh, et, cit, tcls, ra1e,
           et_ac + 1 * CHd, et_ac + 5 * CHd,
           et_ac + 2 * CHd, et_ac + 6 * CHd,
           et_ac + 3 * CHd, et_ac + 7 * CHd,
           hwwbB, et_hwb, x1 + 450, x1b + 450 };

  GP calls[2] = { A, B };
  for (int ci_ = 0; ci_ < 2; ci_++){
    const GP& P = calls[ci_];
    hipMemsetAsync(csum_p, 0, Cc * 16 * 4, stream);
    hipMemsetAsync(ccnt_p, 0, Cc * 16 * 4, stream);
    hipMemsetAsync(x_class, 0, Cc * CHd * 4, stream);
    hipMemsetAsync(outb, 0, (size_t)Nn * CHd * 4, stream);
    k_ndots2<<<Nn, 64, 0, stream>>>(P.xm, P.xo, 600, P.v2m, P.v3m, P.v2o, P.v3o, P.v4,
                                    xnb, pm, po, nv4);
    k_e2sum<<<CB, 256, 0, stream>>>(P.im, P.io, rel, P.ci, pm, po, P.ra1,
                                    es2, csum_p, ccnt_p);
    k_cscan<<<1, 256, 0, stream>>>(ccnt_p, cstart, ccur_p);
    k_cscatter<<<CB, 256, 0, stream>>>(P.ci, P.im, es2, ccur_p, crows, cw);
    k_xclassB<<<Cc * XSPL, 192, 0, stream>>>(cstart, crows, cw, csum_p, xnb, x_class);
    k_classfinal<<<1, 256, 0, stream>>>(x_class, P.acv, nv4, P.cls_ent, outb);
    k_f2b<<<Nn, 64, 0, stream>>>(P.xo, 150, 600, xob, 160);
    k_gemmb<1,1><<<dim3(3, cdiv_h(Nn, 64)), 256, 0, stream>>>(
        xob, 160, Nn, P.hwwb, 160, 150, P.hwb, outb, 150, P.xo, 600, P.x1out, 600,
        P.x1outb, 600);
  }

  // ---- final GAT over x1 ----
  k_s12<<<Nn, 64, 0, stream>>>(x1b, gai, gaj, s1v, s2v);
  k_gat<<<Nn, 256, 0, stream>>>(x1, x1b, csr_ptr, csr_src, s1v, s2v, out);
}